// Round 10
// baseline (10634.406 us; speedup 1.0000x reference)
//
#include <hip/hip_runtime.h>
#include <math.h>

#define NN_ 32768      // nodes
#define NE_ 49152      // edges
#define NG_ 1024       // graphs

__device__ __forceinline__ float sigm(float x) { return 1.f / (1.f + expf(-x)); }

// Kept for harness compatibility (unused).
__global__ void MPNN_78632261256134_kernel() {}

// ---------------- zero fill ----------------
__global__ void k_zero(float* p, int n) {
    int i = blockIdx.x * 256 + threadIdx.x;
    if (i < n) p[i] = 0.f;
}

// ---------------- lin0: node = relu(x @ lin0_W^T + b), all fp32 ----------------
__global__ void k_lin0(const float* x, const float* W, const float* b, float* node) {
    int g = blockIdx.x * 256 + threadIdx.x;   // n*64+d
    int n = g >> 6, d = g & 63;
    const float* xr = x + n * 14;
    const float* wr = W + d * 14;
    float acc = b[d];
    for (int i = 0; i < 14; i++) acc += xr[i] * wr[i];
    node[g] = fmaxf(acc, 0.f);
}

// ---------------- in-degree count ----------------
__global__ void k_cnt(const int* dst, float* cnt) {
    int e = blockIdx.x * 256 + threadIdx.x;
    if (e < NE_) atomicAdd(&cnt[dst[e]], 1.0f);
}

// ---------------- Wt precompute: fp32 [132 k][4096 io] ----------------
// k<128: e2W[io*128+k]; k==128: e2b[io]; k in 129..131: 0
__global__ void k_wt(const float* e2W, const float* e2b, float* Wt) {
    int idx = blockIdx.x * 256 + threadIdx.x;   // < 132*4096
    if (idx >= 132 * 4096) return;
    int k = idx >> 12, io = idx & 4095;
    float v;
    if (k < 128) v = e2W[io * 128 + k];
    else if (k == 128) v = e2b[io];
    else v = 0.f;
    Wt[(size_t)k * 4096 + io] = v;
}

// ---------------- fused NNConv message + scatter (VALU) ----------------
// msg[e,o] = sum_i x[e,i] * ( sum_k He[e,k]*e2W[i*64+o,k] + e2b[i*64+o] )
//          = sum_i sum_{k<132} Hs[e,k] * Wt[k][i*64+o] * x[e,i]  (Hs[128]=1, Hs[129..131]=0)
// block: 16 edges x 256 threads; thread = (edge r = tid>>4, output group o = (tid&15)*4)
__global__ void k_conv(const float* node, const float* ea,
                       const float* e1W, const float* e1b,
                       const float* Wt, const int* src, const int* dst, float* agg) {
    __shared__ float Hs[16][136];   // 132 used
    __shared__ float xs[16][68];    // 64 used
    __shared__ int dst_s[16];

    const int tid = threadIdx.x;
    const int eb = blockIdx.x * 16;
    const int r = tid >> 4;         // edge row 0..15
    const int q = tid & 15;

    {   // He row r, cols q*8 .. q*8+7  (He = relu(ea @ e1W^T + e1b))
        const float* ar = ea + (size_t)(eb + r) * 4;
        float a0 = ar[0], a1 = ar[1], a2 = ar[2], a3 = ar[3];
        for (int j = 0; j < 8; j++) {
            int c = q * 8 + j;
            const float* wr = e1W + c * 4;
            float acc = e1b[c] + a0 * wr[0] + a1 * wr[1] + a2 * wr[2] + a3 * wr[3];
            Hs[r][c] = fmaxf(acc, 0.f);
        }
        int s = src[eb + r];
        const float* nr = node + (size_t)s * 64 + q * 4;
        for (int j = 0; j < 4; j++) xs[r][q * 4 + j] = nr[j];
        if (q == 0) {
            Hs[r][128] = 1.f; Hs[r][129] = 0.f; Hs[r][130] = 0.f; Hs[r][131] = 0.f;
            dst_s[r] = dst[eb + r];
        }
    }
    __syncthreads();

    const int o = q * 4;
    float acc0 = 0.f, acc1 = 0.f, acc2 = 0.f, acc3 = 0.f;

    for (int i = 0; i < 64; i++) {
        float t0 = 0.f, t1 = 0.f, t2 = 0.f, t3 = 0.f;
        const float* wbase = Wt + i * 64 + o;
#pragma unroll 4
        for (int k4 = 0; k4 < 33; k4++) {
            float4 h4 = *(const float4*)&Hs[r][k4 * 4];
            const float* wp = wbase + (size_t)(k4 * 4) * 4096;
            float4 w0 = *(const float4*)(wp);
            float4 w1 = *(const float4*)(wp + 4096);
            float4 w2 = *(const float4*)(wp + 8192);
            float4 w3 = *(const float4*)(wp + 12288);
            t0 += h4.x * w0.x + h4.y * w1.x + h4.z * w2.x + h4.w * w3.x;
            t1 += h4.x * w0.y + h4.y * w1.y + h4.z * w2.y + h4.w * w3.y;
            t2 += h4.x * w0.z + h4.y * w1.z + h4.z * w2.z + h4.w * w3.z;
            t3 += h4.x * w0.w + h4.y * w1.w + h4.z * w2.w + h4.w * w3.w;
        }
        float xv = xs[r][i];
        acc0 += xv * t0; acc1 += xv * t1; acc2 += xv * t2; acc3 += xv * t3;
    }

    float* ap = agg + (size_t)dst_s[r] * 64 + o;
    atomicAdd(ap + 0, acc0);
    atomicAdd(ap + 1, acc1);
    atomicAdd(ap + 2, acc2);
    atomicAdd(ap + 3, acc3);
}

// ---------------- m = relu(agg/cnt + node @ root_W + conv_b) ----------------
__global__ void k_m(const float* agg, const float* cnt, const float* nodeIn,
                    const float* rootW, const float* convb, float* m) {
    int g = blockIdx.x * 256 + threadIdx.x;
    int n = g >> 6, d = g & 63;
    float inv = 1.f / fmaxf(cnt[n], 1.f);
    float acc = agg[g] * inv + convb[d];
    const float* xr = nodeIn + (size_t)n * 64;
    for (int i = 0; i < 64; i++) acc += xr[i] * rootW[i * 64 + d];
    m[g] = fmaxf(acc, 0.f);
}

// ---------------- GRU cell; gWih/gWhh [192,64] row-major ----------------
__global__ void k_gru(const float* m, const float* h,
                      const float* Wih, const float* Whh,
                      const float* bih, const float* bhh, float* hOut) {
    int g = blockIdx.x * 256 + threadIdx.x;
    int n = g >> 6, d = g & 63;
    float ir = bih[d], iz = bih[64 + d], in_ = bih[128 + d];
    float hr = bhh[d], hz = bhh[64 + d], hn = bhh[128 + d];
    const float* mr = m + (size_t)n * 64;
    const float* hrow = h + (size_t)n * 64;
    for (int i = 0; i < 64; i++) {
        float mi = mr[i], hi = hrow[i];
        ir += mi * Wih[d * 64 + i];
        iz += mi * Wih[(64 + d) * 64 + i];
        in_ += mi * Wih[(128 + d) * 64 + i];
        hr += hi * Whh[d * 64 + i];
        hz += hi * Whh[(64 + d) * 64 + i];
        hn += hi * Whh[(128 + d) * 64 + i];
    }
    float r = sigm(ir + hr);
    float z = sigm(iz + hz);
    float nn = tanhf(in_ + r * hn);
    hOut[g] = (1.f - z) * nn + z * hrow[d];
}

// ---------------- Set2Set LSTM cell (per (b,d)) ----------------
__global__ void k_lstm(const float* qstar, const float* hlIn,
                       const float* Wih, const float* Whh,
                       const float* bih, const float* bhh,
                       float* cl, float* hlOut) {
    int g = blockIdx.x * 256 + threadIdx.x;   // b*64+d
    int b = g >> 6, d = g & 63;
    const float* qv = qstar + (size_t)b * 128;
    const float* hr = hlIn + (size_t)b * 64;
    float gate[4];
    for (int gg = 0; gg < 4; gg++) {
        int row = gg * 64 + d;
        float acc = bih[row] + bhh[row];
        const float* wi = Wih + (size_t)row * 128;
        const float* wh = Whh + (size_t)row * 64;
        for (int j = 0; j < 128; j++) acc += qv[j] * wi[j];
        for (int j = 0; j < 64; j++) acc += hr[j] * wh[j];
        gate[gg] = acc;
    }
    float i_ = sigm(gate[0]), f_ = sigm(gate[1]);
    float g_ = tanhf(gate[2]), o_ = sigm(gate[3]);
    float c = f_ * cl[g] + i_ * g_;
    cl[g] = c;
    hlOut[g] = o_ * tanhf(c);
}

// ---------------- e[n] = dot(node[n], q[batch[n]]) (one wave per node) ----------------
__global__ void k_escore(const float* node, const float* q, const int* batch, float* e) {
    int tid = threadIdx.x;
    int n = blockIdx.x * 4 + (tid >> 6);
    int lane = tid & 63;
    int b = batch[n];
    float p = node[(size_t)n * 64 + lane] * q[(size_t)b * 64 + lane];
    for (int o = 32; o > 0; o >>= 1) p += __shfl_xor(p, o);
    if (lane == 0) e[n] = p;
}

// ---------------- segment softmax + weighted readout, one wave per graph ----------------
__global__ void k_pool(const float* node, const float* e, const int* batch,
                       const float* q, float* qstar) {
    int b = blockIdx.x; int lane = threadIdx.x;  // 64 threads
    int lo = 0, hi = NN_;
    while (lo < hi) { int mid = (lo + hi) >> 1; if (batch[mid] < b) lo = mid + 1; else hi = mid; }
    int start = lo;
    lo = start; hi = NN_;
    while (lo < hi) { int mid = (lo + hi) >> 1; if (batch[mid] < b + 1) lo = mid + 1; else hi = mid; }
    int end = lo;
    float r = 0.f;
    if (end > start) {
        float mx = -1e30f;
        for (int n = start + lane; n < end; n += 64) mx = fmaxf(mx, e[n]);
        for (int o = 32; o > 0; o >>= 1) mx = fmaxf(mx, __shfl_xor(mx, o));
        float den = 0.f;
        for (int n = start + lane; n < end; n += 64) den += expf(e[n] - mx);
        for (int o = 32; o > 0; o >>= 1) den += __shfl_xor(den, o);
        float inv = 1.f / den;
        for (int n = start; n < end; n++) {
            float wgt = expf(e[n] - mx) * inv;
            r += wgt * node[(size_t)n * 64 + lane];
        }
    }
    qstar[(size_t)b * 128 + lane] = q[(size_t)b * 64 + lane];
    qstar[(size_t)b * 128 + 64 + lane] = r;
}

// ---------------- head: out = relu(qstar @ fc1^T + b1) @ fc2^T + b2, fp32 out ----------------
__global__ void k_fc(const float* qstar, const float* W1, const float* b1,
                     const float* W2, const float* b2, float* out) {
    __shared__ float hid[128];
    int b = blockIdx.x; int t = threadIdx.x;  // 128 threads
    const float* qr = qstar + (size_t)b * 128;
    float acc = b1[t];
    const float* wr = W1 + (size_t)t * 128;
    for (int k = 0; k < 128; k++) acc += qr[k] * wr[k];
    hid[t] = fmaxf(acc, 0.f);
    __syncthreads();
    if (t < 64) {
        float s = hid[t] * W2[t] + hid[t + 64] * W2[t + 64];
        for (int o = 32; o > 0; o >>= 1) s += __shfl_xor(s, o);
        if (t == 0) out[b] = s + b2[0];
    }
}

extern "C" void kernel_launch(void* const* d_in, const int* in_sizes, int n_in,
                              void* d_out, int out_size, void* d_ws, size_t ws_size,
                              hipStream_t stream) {
    const float* x     = (const float*)d_in[0];
    const int*   ei    = (const int*)d_in[1];
    const float* ea    = (const float*)d_in[2];
    const int*   batch = (const int*)d_in[3];
    const float* lin0W = (const float*)d_in[4];
    const float* lin0b = (const float*)d_in[5];
    const float* e1W   = (const float*)d_in[6];
    const float* e1b   = (const float*)d_in[7];
    const float* e2W   = (const float*)d_in[8];
    const float* e2b   = (const float*)d_in[9];
    const float* rootW = (const float*)d_in[10];
    const float* convb = (const float*)d_in[11];
    const float* gWih  = (const float*)d_in[12];
    const float* gWhh  = (const float*)d_in[13];
    const float* gbih  = (const float*)d_in[14];
    const float* gbhh  = (const float*)d_in[15];
    const float* lWih  = (const float*)d_in[16];
    const float* lWhh  = (const float*)d_in[17];
    const float* lbih  = (const float*)d_in[18];
    const float* lbhh  = (const float*)d_in[19];
    const float* fc1W  = (const float*)d_in[20];
    const float* fc1b  = (const float*)d_in[21];
    const float* fc2W  = (const float*)d_in[22];
    const float* fc2b  = (const float*)d_in[23];
    const int* src = ei;
    const int* dst = ei + NE_;

    // workspace carve (~37 MB total)
    char* p = (char*)d_ws;
    auto alloc = [&](size_t bytes) -> char* {
        char* r = p; p += (bytes + 255) & ~(size_t)255; return r;
    };
    float* Wt     = (float*)alloc((size_t)132 * 4096 * 4);   // 2.16 MB
    float* nodeA  = (float*)alloc((size_t)NN_ * 64 * 4);     // 8.39 MB
    float* nodeB  = (float*)alloc((size_t)NN_ * 64 * 4);     // 8.39 MB
    float* aggb   = (float*)alloc((size_t)NN_ * 64 * 4);     // 8.39 MB
    float* mbuf   = (float*)alloc((size_t)NN_ * 64 * 4);     // 8.39 MB
    float* cnt    = (float*)alloc((size_t)NN_ * 4);
    float* ebuf   = (float*)alloc((size_t)NN_ * 4);
    float* qstar  = (float*)alloc((size_t)NG_ * 128 * 4);    // qstar,hlA,hlB,clb contiguous
    float* hlA    = (float*)alloc((size_t)NG_ * 64 * 4);
    float* hlB    = (float*)alloc((size_t)NG_ * 64 * 4);
    float* clb    = (float*)alloc((size_t)NG_ * 64 * 4);

    k_zero<<<(NN_ + 255) / 256, 256, 0, stream>>>(cnt, NN_);
    k_zero<<<(NG_ * 320 + 255) / 256, 256, 0, stream>>>(qstar, NG_ * 320);  // qstar+hlA+hlB+clb
    k_lin0<<<NN_ * 64 / 256, 256, 0, stream>>>(x, lin0W, lin0b, nodeA);
    k_cnt<<<NE_ / 256, 256, 0, stream>>>(dst, cnt);
    k_wt<<<(132 * 4096 + 255) / 256, 256, 0, stream>>>(e2W, e2b, Wt);

    float* curF = nodeA; float* nxtF = nodeB;
    for (int it = 0; it < 3; it++) {
        k_zero<<<NN_ * 64 / 256, 256, 0, stream>>>(aggb, NN_ * 64);
        k_conv<<<NE_ / 16, 256, 0, stream>>>(curF, ea, e1W, e1b, Wt, src, dst, aggb);
        k_m<<<NN_ * 64 / 256, 256, 0, stream>>>(aggb, cnt, curF, rootW, convb, mbuf);
        k_gru<<<NN_ * 64 / 256, 256, 0, stream>>>(mbuf, curF, gWih, gWhh, gbih, gbhh, nxtF);
        float* tf = curF; curF = nxtF; nxtF = tf;
    }

    float* hcur = hlA; float* hnxt = hlB;
    for (int s = 0; s < 3; s++) {
        k_lstm<<<NG_ * 64 / 256, 256, 0, stream>>>(qstar, hcur, lWih, lWhh, lbih, lbhh, clb, hnxt);
        k_escore<<<NN_ / 4, 256, 0, stream>>>(curF, hnxt, batch, ebuf);
        k_pool<<<NG_, 64, 0, stream>>>(curF, ebuf, batch, hnxt, qstar);
        float* t = hcur; hcur = hnxt; hnxt = t;
    }
    k_fc<<<NG_, 128, 0, stream>>>(qstar, fc1W, fc1b, fc2W, fc2b, (float*)d_out);
}

// Round 11
// 1287.598 us; speedup vs baseline: 8.2591x; 8.2591x over previous
//
#include <hip/hip_runtime.h>
#include <math.h>

#define NN_ 32768      // nodes
#define NE_ 49152      // edges
#define NG_ 1024       // graphs

typedef short bh8 __attribute__((ext_vector_type(8)));   // 8 bf16 bit-patterns (4 VGPR), per verified gfx950 example
typedef float f32x4 __attribute__((ext_vector_type(4)));

__device__ __forceinline__ unsigned short f2bfu(float f) {   // RNE float->bf16 bits
    union { float f; unsigned int i; } x; x.f = f;
    unsigned int u = x.i;
    u += 0x7FFFu + ((u >> 16) & 1u);
    return (unsigned short)(u >> 16);
}
__device__ __forceinline__ float sigm(float x) { return 1.f / (1.f + expf(-x)); }

// Kept for harness compatibility (unused).
__global__ void MPNN_78632261256134_kernel() {}

// ---------------- zero fill ----------------
__global__ void k_zero(float* p, int n) {
    int i = blockIdx.x * 256 + threadIdx.x;
    if (i < n) p[i] = 0.f;
}

// ---------------- lin0: node = relu(x @ lin0_W^T + b) ----------------
__global__ void k_lin0(const float* x, const float* W, const float* b, float* node) {
    int g = blockIdx.x * 256 + threadIdx.x;   // n*64+d
    int n = g >> 6, d = g & 63;
    const float* xr = x + n * 14;
    const float* wr = W + d * 14;
    float acc = b[d];
    for (int i = 0; i < 14; i++) acc += xr[i] * wr[i];
    node[g] = fmaxf(acc, 0.f);
}

// ---------------- in-degree count ----------------
__global__ void k_cnt(const int* dst, float* cnt) {
    int e = blockIdx.x * 256 + threadIdx.x;
    if (e < NE_) atomicAdd(&cnt[dst[e]], 1.0f);
}

// ---------------- transpose [192,64] -> [64,192] fp32 (GRU weights, coalesced reads) -----------
__global__ void k_t192(const float* Win, float* Wout) {
    int t = blockIdx.x * 256 + threadIdx.x;  // 192*64
    if (t < 192 * 64) { int gr = t >> 6, i = t & 63; Wout[i * 192 + gr] = Win[gr * 64 + i]; }
}

// ---------------- Bhat: bf16 [64 slabs][64 o][128 k], granule-XOR swizzled ----------------
// logical B_s[o][k] = e2W[(s*64+o)*128 + k]  (== e2W[idx], layout-preserving)
__global__ void k_bhat(const float* e2W, unsigned short* Bhat) {
    int idx = blockIdx.x * 256 + threadIdx.x;   // < 64*8192
    if (idx >= 64 * 8192) return;
    int s = idx >> 13, r = idx & 8191, o = r >> 7, k = r & 127;
    float v = e2W[idx];
    int g = k >> 3, j = k & 7;
    Bhat[(s << 13) + (o << 7) + (((g ^ (o & 15)) << 3) + j)] = f2bfu(v);
}

// ---------------- gx[n,:] += node[src[e],:] for e->n  (bias factorization) ----------------
__global__ void k_gx(const float* node, const int* src, const int* dst, float* gx) {
    int g = blockIdx.x * 256 + threadIdx.x;   // e*64+d
    int e = g >> 6, d = g & 63;
    atomicAdd(&gx[(size_t)dst[e] * 64 + d], node[(size_t)src[e] * 64 + d]);
}

// ---------------- MFMA NNConv message GEMM + scatter ----------------
// msg[e,o] = sum_s x[e,s] * ( He[e,:] . e2W[s*64+o, :] ),  He = relu(ea@e1W^T+e1b) in A-regs.
// block: 128 edges, 4 waves; wave: M=32 (2 tiles) x N=64 (4 tiles); 64 K-slabs of 128.
__global__ __launch_bounds__(256) void k_convm(const float* __restrict__ node,
                                               const float* __restrict__ ea,
                                               const float* __restrict__ e1W,
                                               const float* __restrict__ e1b,
                                               const unsigned short* __restrict__ Bhat,
                                               const int* __restrict__ src,
                                               const int* __restrict__ dst,
                                               float* __restrict__ agg) {
    __shared__ __align__(16) float xT[64 * 132];          // xT[i][e], stride 132 (528B rows, 16B-aligned)
    __shared__ __align__(16) unsigned short Bs[8192];     // one swizzled slab (16 KB)
    __shared__ int dst_s[128];

    const int tid = threadIdx.x;
    const int eb = blockIdx.x * 128;

    {   // xT fill: thread = (edge r = tid>>1, half c2 = tid&1), 32 floats each
        int r = tid >> 1, c2 = tid & 1;
        int s = src[eb + r];
        const float* nr = node + (size_t)s * 64 + c2 * 32;
#pragma unroll
        for (int j = 0; j < 32; j++) xT[(c2 * 32 + j) * 132 + r] = nr[j];
        if (tid < 128) dst_s[tid] = dst[eb + tid];
    }

    const int lane = tid & 63, w = tid >> 6;
    const int quad = lane >> 4, mrow = lane & 15;

    // A-frags (He, bf16) computed directly into registers; constant across all slabs
    bh8 af[2][4];
#pragma unroll
    for (int mt = 0; mt < 2; mt++) {
        int e = eb + w * 32 + mt * 16 + mrow;
        const float* ar = ea + (size_t)e * 4;
        float a0 = ar[0], a1 = ar[1], a2 = ar[2], a3 = ar[3];
#pragma unroll
        for (int t = 0; t < 4; t++) {
            union { bh8 v; unsigned short u[8]; } tmp;
#pragma unroll
            for (int j = 0; j < 8; j++) {
                int c = t * 32 + quad * 8 + j;
                const float* wr = e1W + c * 4;
                float h = e1b[c] + a0 * wr[0] + a1 * wr[1] + a2 * wr[2] + a3 * wr[3];
                tmp.u[j] = f2bfu(fmaxf(h, 0.f));
            }
            af[mt][t] = tmp.v;
        }
    }
    __syncthreads();   // xT, dst_s visible

    const f32x4 z4 = {0.f, 0.f, 0.f, 0.f};
    f32x4 msg[2][4];
#pragma unroll
    for (int mt = 0; mt < 2; mt++)
#pragma unroll
        for (int nt = 0; nt < 4; nt++) msg[mt][nt] = z4;

    for (int s = 0; s < 64; s++) {
        // prefetch slab into regs (overlaps previous compute), then stage to LDS
        const unsigned short* gB = Bhat + (s << 13) + w * 2048 + lane * 8;
        uint4 stg[4];
#pragma unroll
        for (int q = 0; q < 4; q++) stg[q] = *(const uint4*)(gB + q * 512);
        __syncthreads();
        {
            unsigned short* lB = Bs + w * 2048 + lane * 8;
#pragma unroll
            for (int q = 0; q < 4; q++) *(uint4*)(lB + q * 512) = stg[q];
        }
        __syncthreads();

        f32x4 acc[2][4];
#pragma unroll
        for (int t = 0; t < 4; t++) {
            bh8 bf[4];
            const int g = t * 4 + quad;
#pragma unroll
            for (int nt = 0; nt < 4; nt++) {
                const int o = nt * 16 + mrow;
                bf[nt] = *(const bh8*)(const void*)(Bs + o * 128 + ((g ^ (o & 15)) << 3));
            }
#pragma unroll
            for (int mt = 0; mt < 2; mt++)
#pragma unroll
                for (int nt = 0; nt < 4; nt++)
                    acc[mt][nt] = __builtin_amdgcn_mfma_f32_16x16x32_bf16(
                        af[mt][t], bf[nt], (t == 0) ? z4 : acc[mt][nt], 0, 0, 0);
        }
        // drain: msg += x[e,s] * C_s   (x fp32 from LDS, broadcast)
#pragma unroll
        for (int mt = 0; mt < 2; mt++) {
            f32x4 xv = *(const f32x4*)(const void*)(xT + s * 132 + w * 32 + mt * 16 + quad * 4);
#pragma unroll
            for (int nt = 0; nt < 4; nt++)
#pragma unroll
                for (int r = 0; r < 4; r++)
                    msg[mt][nt][r] += xv[r] * acc[mt][nt][r];
        }
    }

    // scatter: C row = edge (quad*4+r), col = o (nt*16+mrow)
#pragma unroll
    for (int mt = 0; mt < 2; mt++)
#pragma unroll
        for (int nt = 0; nt < 4; nt++) {
            const int o = nt * 16 + mrow;
#pragma unroll
            for (int r = 0; r < 4; r++) {
                int e = w * 32 + mt * 16 + quad * 4 + r;
                atomicAdd(agg + (size_t)dst_s[e] * 64 + o, msg[mt][nt][r]);
            }
        }
}

// ---------------- m = relu((agg + gx@e2b)/cnt + node@root_W + conv_b) ----------------
__global__ void k_m(const float* agg, const float* gx, const float* cnt, const float* nodeIn,
                    const float* rootW, const float* e2b, const float* convb, float* m) {
    int g = blockIdx.x * 256 + threadIdx.x;
    int n = g >> 6, d = g & 63;
    float inv = 1.f / fmaxf(cnt[n], 1.f);
    const float* gxr = gx + (size_t)n * 64;
    const float* xr = nodeIn + (size_t)n * 64;
    float bias = 0.f, root = 0.f;
    for (int i = 0; i < 64; i++) {
        bias += gxr[i] * e2b[i * 64 + d];
        root += xr[i] * rootW[i * 64 + d];
    }
    m[g] = fmaxf((agg[g] + bias) * inv + convb[d] + root, 0.f);
}

// ---------------- GRU cell; WihT/WhhT [64,192] i-major (coalesced) ----------------
__global__ void k_gru(const float* m, const float* h,
                      const float* WihT, const float* WhhT,
                      const float* bih, const float* bhh, float* hOut) {
    int g = blockIdx.x * 256 + threadIdx.x;
    int n = g >> 6, d = g & 63;
    float ir = bih[d], iz = bih[64 + d], in_ = bih[128 + d];
    float hr = bhh[d], hz = bhh[64 + d], hn = bhh[128 + d];
    const float* mr = m + (size_t)n * 64;
    const float* hrow = h + (size_t)n * 64;
    for (int i = 0; i < 64; i++) {
        float mi = mr[i], hi = hrow[i];
        ir += mi * WihT[i * 192 + d];
        iz += mi * WihT[i * 192 + 64 + d];
        in_ += mi * WihT[i * 192 + 128 + d];
        hr += hi * WhhT[i * 192 + d];
        hz += hi * WhhT[i * 192 + 64 + d];
        hn += hi * WhhT[i * 192 + 128 + d];
    }
    float r = sigm(ir + hr);
    float z = sigm(iz + hz);
    float nn = tanhf(in_ + r * hn);
    hOut[g] = (1.f - z) * nn + z * hrow[d];
}

// ---------------- Set2Set LSTM cell (per (b,d)) ----------------
__global__ void k_lstm(const float* qstar, const float* hlIn,
                       const float* Wih, const float* Whh,
                       const float* bih, const float* bhh,
                       float* cl, float* hlOut) {
    int g = blockIdx.x * 256 + threadIdx.x;   // b*64+d
    int b = g >> 6, d = g & 63;
    const float* qv = qstar + (size_t)b * 128;
    const float* hr = hlIn + (size_t)b * 64;
    float gate[4];
    for (int gg = 0; gg < 4; gg++) {
        int row = gg * 64 + d;
        float acc = bih[row] + bhh[row];
        const float* wi = Wih + (size_t)row * 128;
        const float* wh = Whh + (size_t)row * 64;
        for (int j = 0; j < 128; j++) acc += qv[j] * wi[j];
        for (int j = 0; j < 64; j++) acc += hr[j] * wh[j];
        gate[gg] = acc;
    }
    float i_ = sigm(gate[0]), f_ = sigm(gate[1]);
    float g_ = tanhf(gate[2]), o_ = sigm(gate[3]);
    float c = f_ * cl[g] + i_ * g_;
    cl[g] = c;
    hlOut[g] = o_ * tanhf(c);
}

// ---------------- e[n] = dot(node[n], q[batch[n]]) ----------------
__global__ void k_escore(const float* node, const float* q, const int* batch, float* e) {
    int tid = threadIdx.x;
    int n = blockIdx.x * 4 + (tid >> 6);
    int lane = tid & 63;
    int b = batch[n];
    float p = node[(size_t)n * 64 + lane] * q[(size_t)b * 64 + lane];
    for (int o = 32; o > 0; o >>= 1) p += __shfl_xor(p, o);
    if (lane == 0) e[n] = p;
}

// ---------------- segment softmax + weighted readout, one wave per graph ----------------
__global__ void k_pool(const float* node, const float* e, const int* batch,
                       const float* q, float* qstar) {
    int b = blockIdx.x; int lane = threadIdx.x;  // 64 threads
    int lo = 0, hi = NN_;
    while (lo < hi) { int mid = (lo + hi) >> 1; if (batch[mid] < b) lo = mid + 1; else hi = mid; }
    int start = lo;
    lo = start; hi = NN_;
    while (lo < hi) { int mid = (lo + hi) >> 1; if (batch[mid] < b + 1) lo = mid + 1; else hi = mid; }
    int end = lo;
    float r = 0.f;
    if (end > start) {
        float mx = -1e30f;
        for (int n = start + lane; n < end; n += 64) mx = fmaxf(mx, e[n]);
        for (int o = 32; o > 0; o >>= 1) mx = fmaxf(mx, __shfl_xor(mx, o));
        float den = 0.f;
        for (int n = start + lane; n < end; n += 64) den += expf(e[n] - mx);
        for (int o = 32; o > 0; o >>= 1) den += __shfl_xor(den, o);
        float inv = 1.f / den;
        for (int n = start; n < end; n++) {
            float wgt = expf(e[n] - mx) * inv;
            r += wgt * node[(size_t)n * 64 + lane];
        }
    }
    qstar[(size_t)b * 128 + lane] = q[(size_t)b * 64 + lane];
    qstar[(size_t)b * 128 + 64 + lane] = r;
}

// ---------------- head ----------------
__global__ void k_fc(const float* qstar, const float* W1, const float* b1,
                     const float* W2, const float* b2, float* out) {
    __shared__ float hid[128];
    int b = blockIdx.x; int t = threadIdx.x;  // 128 threads
    const float* qr = qstar + (size_t)b * 128;
    float acc = b1[t];
    const float* wr = W1 + (size_t)t * 128;
    for (int k = 0; k < 128; k++) acc += qr[k] * wr[k];
    hid[t] = fmaxf(acc, 0.f);
    __syncthreads();
    if (t < 64) {
        float s = hid[t] * W2[t] + hid[t + 64] * W2[t + 64];
        for (int o = 32; o > 0; o >>= 1) s += __shfl_xor(s, o);
        if (t == 0) out[b] = s + b2[0];
    }
}

extern "C" void kernel_launch(void* const* d_in, const int* in_sizes, int n_in,
                              void* d_out, int out_size, void* d_ws, size_t ws_size,
                              hipStream_t stream) {
    const float* x     = (const float*)d_in[0];
    const int*   ei    = (const int*)d_in[1];
    const float* ea    = (const float*)d_in[2];
    const int*   batch = (const int*)d_in[3];
    const float* lin0W = (const float*)d_in[4];
    const float* lin0b = (const float*)d_in[5];
    const float* e1W   = (const float*)d_in[6];
    const float* e1b   = (const float*)d_in[7];
    const float* e2W   = (const float*)d_in[8];
    const float* e2b   = (const float*)d_in[9];
    const float* rootW = (const float*)d_in[10];
    const float* convb = (const float*)d_in[11];
    const float* gWih  = (const float*)d_in[12];
    const float* gWhh  = (const float*)d_in[13];
    const float* gbih  = (const float*)d_in[14];
    const float* gbhh  = (const float*)d_in[15];
    const float* lWih  = (const float*)d_in[16];
    const float* lWhh  = (const float*)d_in[17];
    const float* lbih  = (const float*)d_in[18];
    const float* lbhh  = (const float*)d_in[19];
    const float* fc1W  = (const float*)d_in[20];
    const float* fc1b  = (const float*)d_in[21];
    const float* fc2W  = (const float*)d_in[22];
    const float* fc2b  = (const float*)d_in[23];
    const int* src = ei;
    const int* dst = ei + NE_;

    // workspace carve (~45 MB)
    char* p = (char*)d_ws;
    auto alloc = [&](size_t bytes) -> char* {
        char* r = p; p += (bytes + 255) & ~(size_t)255; return r;
    };
    unsigned short* Bhat = (unsigned short*)alloc((size_t)64 * 8192 * 2);  // 1.05 MB
    float* nodeA  = (float*)alloc((size_t)NN_ * 64 * 4);
    float* nodeB  = (float*)alloc((size_t)NN_ * 64 * 4);
    float* aggb   = (float*)alloc((size_t)2 * NN_ * 64 * 4);   // agg | gx, contiguous for one zero
    float* gxb    = aggb + (size_t)NN_ * 64;
    float* mbuf   = (float*)alloc((size_t)NN_ * 64 * 4);
    float* cnt    = (float*)alloc((size_t)NN_ * 4);
    float* ebuf   = (float*)alloc((size_t)NN_ * 4);
    float* WihT   = (float*)alloc(192 * 64 * 4);
    float* WhhT   = (float*)alloc(192 * 64 * 4);
    float* qstar  = (float*)alloc((size_t)NG_ * 128 * 4);      // qstar,hlA,hlB,clb contiguous
    float* hlA    = (float*)alloc((size_t)NG_ * 64 * 4);
    float* hlB    = (float*)alloc((size_t)NG_ * 64 * 4);
    float* clb    = (float*)alloc((size_t)NG_ * 64 * 4);

    k_zero<<<(NN_ + 255) / 256, 256, 0, stream>>>(cnt, NN_);
    k_zero<<<(NG_ * 320 + 255) / 256, 256, 0, stream>>>(qstar, NG_ * 320);
    k_lin0<<<NN_ * 64 / 256, 256, 0, stream>>>(x, lin0W, lin0b, nodeA);
    k_cnt<<<NE_ / 256, 256, 0, stream>>>(dst, cnt);
    k_t192<<<48, 256, 0, stream>>>(gWih, WihT);
    k_t192<<<48, 256, 0, stream>>>(gWhh, WhhT);
    k_bhat<<<64 * 8192 / 256, 256, 0, stream>>>(e2W, Bhat);

    float* curF = nodeA; float* nxtF = nodeB;
    for (int it = 0; it < 3; it++) {
        k_zero<<<2 * NN_ * 64 / 256, 256, 0, stream>>>(aggb, 2 * NN_ * 64);
        k_gx<<<NE_ * 64 / 256, 256, 0, stream>>>(curF, src, dst, gxb);
        k_convm<<<NE_ / 128, 256, 0, stream>>>(curF, ea, e1W, e1b, Bhat, src, dst, aggb);
        k_m<<<NN_ * 64 / 256, 256, 0, stream>>>(aggb, gxb, cnt, curF, rootW, e2b, convb, mbuf);
        k_gru<<<NN_ * 64 / 256, 256, 0, stream>>>(mbuf, curF, WihT, WhhT, gbih, gbhh, nxtF);
        float* tf = curF; curF = nxtF; nxtF = tf;
    }

    float* hcur = hlA; float* hnxt = hlB;
    for (int s = 0; s < 3; s++) {
        k_lstm<<<NG_ * 64 / 256, 256, 0, stream>>>(qstar, hcur, lWih, lWhh, lbih, lbhh, clb, hnxt);
        k_escore<<<NN_ / 4, 256, 0, stream>>>(curF, hnxt, batch, ebuf);
        k_pool<<<NG_, 64, 0, stream>>>(curF, ebuf, batch, hnxt, qstar);
        float* t = hcur; hcur = hnxt; hnxt = t;
    }
    k_fc<<<NG_, 128, 0, stream>>>(qstar, fc1W, fc1b, fc2W, fc2b, (float*)d_out);
}

// Round 12
// 1094.587 us; speedup vs baseline: 9.7154x; 1.1763x over previous
//
#include <hip/hip_runtime.h>
#include <math.h>

#define NN_ 32768      // nodes
#define NE_ 49152      // edges
#define NG_ 1024       // graphs

typedef short bh8 __attribute__((ext_vector_type(8)));   // 8 bf16 bit-patterns (4 VGPR)
typedef float f32x4 __attribute__((ext_vector_type(4)));

__device__ __forceinline__ unsigned short f2bfu(float f) {   // RNE float->bf16 bits
    union { float f; unsigned int i; } x; x.f = f;
    unsigned int u = x.i;
    u += 0x7FFFu + ((u >> 16) & 1u);
    return (unsigned short)(u >> 16);
}
__device__ __forceinline__ float sigm(float x) { return 1.f / (1.f + expf(-x)); }

// Kept for harness compatibility (unused).
__global__ void MPNN_78632261256134_kernel() {}

// ---------------- zero fill ----------------
__global__ void k_zero(float* p, int n) {
    int i = blockIdx.x * 256 + threadIdx.x;
    if (i < n) p[i] = 0.f;
}

// ---------------- lin0 ----------------
__global__ void k_lin0(const float* x, const float* W, const float* b, float* node) {
    int g = blockIdx.x * 256 + threadIdx.x;   // n*64+d
    int n = g >> 6, d = g & 63;
    const float* xr = x + n * 14;
    const float* wr = W + d * 14;
    float acc = b[d];
    for (int i = 0; i < 14; i++) acc += xr[i] * wr[i];
    node[g] = fmaxf(acc, 0.f);
}

// ---------------- in-degree count ----------------
__global__ void k_cnt(const int* dst, float* cnt) {
    int e = blockIdx.x * 256 + threadIdx.x;
    if (e < NE_) atomicAdd(&cnt[dst[e]], 1.0f);
}

// ---------------- transposes (coalesced weight reads) ----------------
__global__ void k_t192(const float* Win, float* Wout) {   // [192,64] -> [64,192]
    int t = blockIdx.x * 256 + threadIdx.x;
    if (t < 192 * 64) { int gr = t >> 6, i = t & 63; Wout[i * 192 + gr] = Win[gr * 64 + i]; }
}
__global__ void k_tlih(const float* Win, float* Wout) {   // [256,128] -> [128,256]
    int t = blockIdx.x * 256 + threadIdx.x;
    if (t < 256 * 128) { int r = t >> 7, c = t & 127; Wout[c * 256 + r] = Win[t]; }
}
__global__ void k_tlhh(const float* Win, float* Wout) {   // [256,64] -> [64,256]
    int t = blockIdx.x * 256 + threadIdx.x;
    if (t < 256 * 64) { int r = t >> 6, c = t & 63; Wout[c * 256 + r] = Win[t]; }
}

// ---------------- Bhat: bf16 [64 slabs][64 o][128 k], granule-XOR swizzled ----------------
__global__ void k_bhat(const float* e2W, unsigned short* Bhat) {
    int idx = blockIdx.x * 256 + threadIdx.x;   // < 64*8192
    if (idx >= 64 * 8192) return;
    int s = idx >> 13, r = idx & 8191, o = r >> 7, k = r & 127;
    float v = e2W[idx];
    int g = k >> 3, j = k & 7;
    Bhat[(s << 13) + (o << 7) + (((g ^ (o & 15)) << 3) + j)] = f2bfu(v);
}

// ---------------- MFMA NNConv message GEMM + scatter (slab-split 2-way) ----------------
// msg[e,o] = sum_s x[e,s] * ( He[e,:].e2W[s*64+o,:] + e2b[s*64+o] ), He in A-regs.
// block: 128 edges x 32 slabs (sq = blockIdx&1); 4 waves, wave: M=32 x N=64.
__global__ __launch_bounds__(256) void k_convm(const float* __restrict__ node,
                                               const float* __restrict__ ea,
                                               const float* __restrict__ e1W,
                                               const float* __restrict__ e1b,
                                               const float* __restrict__ e2b,
                                               const unsigned short* __restrict__ Bhat,
                                               const int* __restrict__ src,
                                               const int* __restrict__ dst,
                                               float* __restrict__ agg) {
    __shared__ __align__(16) float xT[32 * 132];          // xT[s_local][e], 16.9 KB
    __shared__ __align__(16) unsigned short Bs[8192];     // one swizzled slab (16 KB)
    __shared__ int dst_s[128];

    const int tid = threadIdx.x;
    const int eb = (blockIdx.x >> 1) * 128;
    const int sq = blockIdx.x & 1;                        // slab half: s in [sq*32, sq*32+32)

    {   // xT fill: thread = (edge r = tid>>1, half c2 = tid&1), 16 floats each
        int r = tid >> 1, c2 = tid & 1;
        int s = src[eb + r];
        const float* nr = node + (size_t)s * 64 + sq * 32 + c2 * 16;
#pragma unroll
        for (int j = 0; j < 16; j++) xT[(c2 * 16 + j) * 132 + r] = nr[j];
        if (tid < 128) dst_s[tid] = dst[eb + tid];
    }

    const int lane = tid & 63, w = tid >> 6;
    const int quad = lane >> 4, mrow = lane & 15;

    // A-frags (He, bf16) computed directly into registers; constant across slabs
    bh8 af[2][4];
#pragma unroll
    for (int mt = 0; mt < 2; mt++) {
        int e = eb + w * 32 + mt * 16 + mrow;
        const float* ar = ea + (size_t)e * 4;
        float a0 = ar[0], a1 = ar[1], a2 = ar[2], a3 = ar[3];
#pragma unroll
        for (int t = 0; t < 4; t++) {
            union { bh8 v; unsigned short u[8]; } tmp;
#pragma unroll
            for (int j = 0; j < 8; j++) {
                int c = t * 32 + quad * 8 + j;
                const float* wr = e1W + c * 4;
                float h = e1b[c] + a0 * wr[0] + a1 * wr[1] + a2 * wr[2] + a3 * wr[3];
                tmp.u[j] = f2bfu(fmaxf(h, 0.f));
            }
            af[mt][t] = tmp.v;
        }
    }
    __syncthreads();   // xT, dst_s visible

    const f32x4 z4 = {0.f, 0.f, 0.f, 0.f};
    f32x4 msg[2][4];
#pragma unroll
    for (int mt = 0; mt < 2; mt++)
#pragma unroll
        for (int nt = 0; nt < 4; nt++) msg[mt][nt] = z4;

    for (int s5 = 0; s5 < 32; s5++) {
        const int s = sq * 32 + s5;
        // prefetch slab into regs (overlaps previous compute), then stage to LDS
        const unsigned short* gB = Bhat + (s << 13) + w * 2048 + lane * 8;
        uint4 stg[4];
#pragma unroll
        for (int q = 0; q < 4; q++) stg[q] = *(const uint4*)(gB + q * 512);
        // bias row for this slab (L2-hot)
        float bb[4];
#pragma unroll
        for (int nt = 0; nt < 4; nt++) bb[nt] = e2b[(s << 6) + nt * 16 + mrow];
        __syncthreads();
        {
            unsigned short* lB = Bs + w * 2048 + lane * 8;
#pragma unroll
            for (int q = 0; q < 4; q++) *(uint4*)(lB + q * 512) = stg[q];
        }
        __syncthreads();

        f32x4 acc[2][4];
#pragma unroll
        for (int t = 0; t < 4; t++) {
            bh8 bf[4];
            const int g = t * 4 + quad;
#pragma unroll
            for (int nt = 0; nt < 4; nt++) {
                const int o = nt * 16 + mrow;
                bf[nt] = *(const bh8*)(const void*)(Bs + o * 128 + ((g ^ (o & 15)) << 3));
            }
#pragma unroll
            for (int mt = 0; mt < 2; mt++)
#pragma unroll
                for (int nt = 0; nt < 4; nt++)
                    acc[mt][nt] = __builtin_amdgcn_mfma_f32_16x16x32_bf16(
                        af[mt][t], bf[nt], (t == 0) ? z4 : acc[mt][nt], 0, 0, 0);
        }
        // drain: msg += x[e,s] * (C_s + e2b_s)
#pragma unroll
        for (int mt = 0; mt < 2; mt++) {
            f32x4 xv = *(const f32x4*)(const void*)(xT + s5 * 132 + w * 32 + mt * 16 + quad * 4);
#pragma unroll
            for (int nt = 0; nt < 4; nt++)
#pragma unroll
                for (int r = 0; r < 4; r++)
                    msg[mt][nt][r] += xv[r] * (acc[mt][nt][r] + bb[nt]);
        }
    }

    // scatter partial msg (this block's 32-slab contribution)
#pragma unroll
    for (int mt = 0; mt < 2; mt++)
#pragma unroll
        for (int nt = 0; nt < 4; nt++) {
            const int o = nt * 16 + mrow;
#pragma unroll
            for (int r = 0; r < 4; r++) {
                int e = w * 32 + mt * 16 + quad * 4 + r;
                atomicAdd(agg + (size_t)dst_s[e] * 64 + o, msg[mt][nt][r]);
            }
        }
}

// ---------------- fused m+GRU: m = relu(agg/cnt + node@rootW + convb); h' = GRU(m,h) --------
// block = 4 nodes x 64 d; m staged in LDS
__global__ void k_mgru(const float* agg, const float* cnt, const float* node,
                       const float* rootW, const float* convb,
                       const float* WihT, const float* WhhT,
                       const float* bih, const float* bhh, float* hOut) {
    __shared__ float ms[4][68];
    int g = blockIdx.x * 256 + threadIdx.x;
    int n = g >> 6, d = g & 63, sub = threadIdx.x >> 6;
    const float* hrow = node + (size_t)n * 64;
    {
        float inv = 1.f / fmaxf(cnt[n], 1.f);
        float root = 0.f;
        for (int i = 0; i < 64; i++) root += hrow[i] * rootW[i * 64 + d];
        ms[sub][d] = fmaxf(agg[g] * inv + convb[d] + root, 0.f);
    }
    __syncthreads();
    float ir = bih[d], iz = bih[64 + d], in_ = bih[128 + d];
    float hr = bhh[d], hz = bhh[64 + d], hn = bhh[128 + d];
    const float* mr = ms[sub];
    for (int i = 0; i < 64; i++) {
        float mi = mr[i], hi = hrow[i];
        ir += mi * WihT[i * 192 + d];
        iz += mi * WihT[i * 192 + 64 + d];
        in_ += mi * WihT[i * 192 + 128 + d];
        hr += hi * WhhT[i * 192 + d];
        hz += hi * WhhT[i * 192 + 64 + d];
        hn += hi * WhhT[i * 192 + 128 + d];
    }
    float r = sigm(ir + hr);
    float z = sigm(iz + hz);
    float nn = tanhf(in_ + r * hn);
    hOut[g] = (1.f - z) * nn + z * hrow[d];
}

// ---------------- Set2Set LSTM cell; WihT2 [128,256], WhhT2 [64,256] (coalesced) -----------
__global__ void k_lstm(const float* qstar, const float* hlIn,
                       const float* WihT2, const float* WhhT2,
                       const float* bih, const float* bhh,
                       float* cl, float* hlOut) {
    int g = blockIdx.x * 256 + threadIdx.x;   // b*64+d
    int b = g >> 6, d = g & 63;
    const float* qv = qstar + (size_t)b * 128;
    const float* hr = hlIn + (size_t)b * 64;
    float gate[4];
    for (int gg = 0; gg < 4; gg++) {
        int row = gg * 64 + d;
        float acc = bih[row] + bhh[row];
        for (int j = 0; j < 128; j++) acc += qv[j] * WihT2[j * 256 + row];
        for (int j = 0; j < 64; j++) acc += hr[j] * WhhT2[j * 256 + row];
        gate[gg] = acc;
    }
    float i_ = sigm(gate[0]), f_ = sigm(gate[1]);
    float g_ = tanhf(gate[2]), o_ = sigm(gate[3]);
    float c = f_ * cl[g] + i_ * g_;
    cl[g] = c;
    hlOut[g] = o_ * tanhf(c);
}

// ---------------- e[n] = dot(node[n], q[batch[n]]) ----------------
__global__ void k_escore(const float* node, const float* q, const int* batch, float* e) {
    int tid = threadIdx.x;
    int n = blockIdx.x * 4 + (tid >> 6);
    int lane = tid & 63;
    int b = batch[n];
    float p = node[(size_t)n * 64 + lane] * q[(size_t)b * 64 + lane];
    for (int o = 32; o > 0; o >>= 1) p += __shfl_xor(p, o);
    if (lane == 0) e[n] = p;
}

// ---------------- segment softmax + weighted readout, one wave per graph ----------------
__global__ void k_pool(const float* node, const float* e, const int* batch,
                       const float* q, float* qstar) {
    int b = blockIdx.x; int lane = threadIdx.x;  // 64 threads
    int lo = 0, hi = NN_;
    while (lo < hi) { int mid = (lo + hi) >> 1; if (batch[mid] < b) lo = mid + 1; else hi = mid; }
    int start = lo;
    lo = start; hi = NN_;
    while (lo < hi) { int mid = (lo + hi) >> 1; if (batch[mid] < b + 1) lo = mid + 1; else hi = mid; }
    int end = lo;
    float r = 0.f;
    if (end > start) {
        float mx = -1e30f;
        for (int n = start + lane; n < end; n += 64) mx = fmaxf(mx, e[n]);
        for (int o = 32; o > 0; o >>= 1) mx = fmaxf(mx, __shfl_xor(mx, o));
        float den = 0.f;
        for (int n = start + lane; n < end; n += 64) den += expf(e[n] - mx);
        for (int o = 32; o > 0; o >>= 1) den += __shfl_xor(den, o);
        float inv = 1.f / den;
        for (int n = start; n < end; n++) {
            float wgt = expf(e[n] - mx) * inv;
            r += wgt * node[(size_t)n * 64 + lane];
        }
    }
    qstar[(size_t)b * 128 + lane] = q[(size_t)b * 64 + lane];
    qstar[(size_t)b * 128 + 64 + lane] = r;
}

// ---------------- head ----------------
__global__ void k_fc(const float* qstar, const float* W1, const float* b1,
                     const float* W2, const float* b2, float* out) {
    __shared__ float hid[128];
    int b = blockIdx.x; int t = threadIdx.x;  // 128 threads
    const float* qr = qstar + (size_t)b * 128;
    float acc = b1[t];
    const float* wr = W1 + (size_t)t * 128;
    for (int k = 0; k < 128; k++) acc += qr[k] * wr[k];
    hid[t] = fmaxf(acc, 0.f);
    __syncthreads();
    if (t < 64) {
        float s = hid[t] * W2[t] + hid[t + 64] * W2[t + 64];
        for (int o = 32; o > 0; o >>= 1) s += __shfl_xor(s, o);
        if (t == 0) out[b] = s + b2[0];
    }
}

extern "C" void kernel_launch(void* const* d_in, const int* in_sizes, int n_in,
                              void* d_out, int out_size, void* d_ws, size_t ws_size,
                              hipStream_t stream) {
    const float* x     = (const float*)d_in[0];
    const int*   ei    = (const int*)d_in[1];
    const float* ea    = (const float*)d_in[2];
    const int*   batch = (const int*)d_in[3];
    const float* lin0W = (const float*)d_in[4];
    const float* lin0b = (const float*)d_in[5];
    const float* e1W   = (const float*)d_in[6];
    const float* e1b   = (const float*)d_in[7];
    const float* e2W   = (const float*)d_in[8];
    const float* e2b   = (const float*)d_in[9];
    const float* rootW = (const float*)d_in[10];
    const float* convb = (const float*)d_in[11];
    const float* gWih  = (const float*)d_in[12];
    const float* gWhh  = (const float*)d_in[13];
    const float* gbih  = (const float*)d_in[14];
    const float* gbhh  = (const float*)d_in[15];
    const float* lWih  = (const float*)d_in[16];
    const float* lWhh  = (const float*)d_in[17];
    const float* lbih  = (const float*)d_in[18];
    const float* lbhh  = (const float*)d_in[19];
    const float* fc1W  = (const float*)d_in[20];
    const float* fc1b  = (const float*)d_in[21];
    const float* fc2W  = (const float*)d_in[22];
    const float* fc2b  = (const float*)d_in[23];
    const int* src = ei;
    const int* dst = ei + NE_;

    // workspace carve (~28 MB)
    char* p = (char*)d_ws;
    auto alloc = [&](size_t bytes) -> char* {
        char* r = p; p += (bytes + 255) & ~(size_t)255; return r;
    };
    unsigned short* Bhat = (unsigned short*)alloc((size_t)64 * 8192 * 2);
    float* nodeA  = (float*)alloc((size_t)NN_ * 64 * 4);
    float* nodeB  = (float*)alloc((size_t)NN_ * 64 * 4);
    float* aggb   = (float*)alloc((size_t)NN_ * 64 * 4);
    float* cnt    = (float*)alloc((size_t)NN_ * 4);
    float* ebuf   = (float*)alloc((size_t)NN_ * 4);
    float* WihT   = (float*)alloc(192 * 64 * 4);
    float* WhhT   = (float*)alloc(192 * 64 * 4);
    float* WihT2  = (float*)alloc(256 * 128 * 4);
    float* WhhT2  = (float*)alloc(256 * 64 * 4);
    float* qstar  = (float*)alloc((size_t)NG_ * 128 * 4);  // qstar,hlA,hlB,clb contiguous
    float* hlA    = (float*)alloc((size_t)NG_ * 64 * 4);
    float* hlB    = (float*)alloc((size_t)NG_ * 64 * 4);
    float* clb    = (float*)alloc((size_t)NG_ * 64 * 4);

    k_zero<<<(NN_ + 255) / 256, 256, 0, stream>>>(cnt, NN_);
    k_zero<<<(NG_ * 320 + 255) / 256, 256, 0, stream>>>(qstar, NG_ * 320);
    k_lin0<<<NN_ * 64 / 256, 256, 0, stream>>>(x, lin0W, lin0b, nodeA);
    k_cnt<<<NE_ / 256, 256, 0, stream>>>(dst, cnt);
    k_t192<<<48, 256, 0, stream>>>(gWih, WihT);
    k_t192<<<48, 256, 0, stream>>>(gWhh, WhhT);
    k_tlih<<<128, 256, 0, stream>>>(lWih, WihT2);
    k_tlhh<<<64, 256, 0, stream>>>(lWhh, WhhT2);
    k_bhat<<<64 * 8192 / 256, 256, 0, stream>>>(e2W, Bhat);

    float* curF = nodeA; float* nxtF = nodeB;
    for (int it = 0; it < 3; it++) {
        k_zero<<<NN_ * 64 / 256, 256, 0, stream>>>(aggb, NN_ * 64);
        k_convm<<<(NE_ / 128) * 2, 256, 0, stream>>>(curF, ea, e1W, e1b, e2b, Bhat, src, dst, aggb);
        k_mgru<<<NN_ * 64 / 256, 256, 0, stream>>>(aggb, cnt, curF, rootW, convb,
                                                   WihT, WhhT, gbih, gbhh, nxtF);
        float* tf = curF; curF = nxtF; nxtF = tf;
    }

    float* hcur = hlA; float* hnxt = hlB;
    for (int s = 0; s < 3; s++) {
        k_lstm<<<NG_ * 64 / 256, 256, 0, stream>>>(qstar, hcur, WihT2, WhhT2, lbih, lbhh, clb, hnxt);
        k_escore<<<NN_ / 4, 256, 0, stream>>>(curF, hnxt, batch, ebuf);
        k_pool<<<NG_, 64, 0, stream>>>(curF, ebuf, batch, hnxt, qstar);
        float* t = hcur; hcur = hnxt; hnxt = t;
    }
    k_fc<<<NG_, 128, 0, stream>>>(qstar, fc1W, fc1b, fc2W, fc2b, (float*)d_out);
}

// Round 13
// 846.241 us; speedup vs baseline: 12.5666x; 1.2935x over previous
//
#include <hip/hip_runtime.h>
#include <math.h>

#define NN_ 32768      // nodes
#define NE_ 49152      // edges
#define NG_ 1024       // graphs

typedef short bh8 __attribute__((ext_vector_type(8)));   // 8 bf16 bit-patterns (4 VGPR)
typedef float f32x4 __attribute__((ext_vector_type(4)));

__device__ __forceinline__ unsigned short f2bfu(float f) {   // RNE float->bf16 bits
    union { float f; unsigned int i; } x; x.f = f;
    unsigned int u = x.i;
    u += 0x7FFFu + ((u >> 16) & 1u);
    return (unsigned short)(u >> 16);
}
__device__ __forceinline__ float sigm(float x) { return 1.f / (1.f + expf(-x)); }

// Kept for harness compatibility (unused).
__global__ void MPNN_78632261256134_kernel() {}

// ---------------- zero fill ----------------
__global__ void k_zero(float* p, int n) {
    int i = blockIdx.x * 256 + threadIdx.x;
    if (i < n) p[i] = 0.f;
}

// ---------------- lin0 ----------------
__global__ void k_lin0(const float* x, const float* W, const float* b, float* node) {
    int g = blockIdx.x * 256 + threadIdx.x;   // n*64+d
    int n = g >> 6, d = g & 63;
    const float* xr = x + n * 14;
    const float* wr = W + d * 14;
    float acc = b[d];
    for (int i = 0; i < 14; i++) acc += xr[i] * wr[i];
    node[g] = fmaxf(acc, 0.f);
}

// ---------------- in-degree count ----------------
__global__ void k_cnt(const int* dst, float* cnt) {
    int e = blockIdx.x * 256 + threadIdx.x;
    if (e < NE_) atomicAdd(&cnt[dst[e]], 1.0f);
}

// ---------------- transposes (coalesced weight reads) ----------------
__global__ void k_t192(const float* Win, float* Wout) {   // [192,64] -> [64,192]
    int t = blockIdx.x * 256 + threadIdx.x;
    if (t < 192 * 64) { int gr = t >> 6, i = t & 63; Wout[i * 192 + gr] = Win[gr * 64 + i]; }
}
__global__ void k_tlih(const float* Win, float* Wout) {   // [256,128] -> [128,256]
    int t = blockIdx.x * 256 + threadIdx.x;
    if (t < 256 * 128) { int r = t >> 7, c = t & 127; Wout[c * 256 + r] = Win[t]; }
}
__global__ void k_tlhh(const float* Win, float* Wout) {   // [256,64] -> [64,256]
    int t = blockIdx.x * 256 + threadIdx.x;
    if (t < 256 * 64) { int r = t >> 6, c = t & 63; Wout[c * 256 + r] = Win[t]; }
}

// ---------------- Bhat: bf16 [64 slabs][64 o][128 k], granule-XOR swizzled ----------------
__global__ void k_bhat(const float* e2W, unsigned short* Bhat) {
    int idx = blockIdx.x * 256 + threadIdx.x;   // < 64*8192
    if (idx >= 64 * 8192) return;
    int s = idx >> 13, r = idx & 8191, o = r >> 7, k = r & 127;
    float v = e2W[idx];
    int g = k >> 3, j = k & 7;
    Bhat[(s << 13) + (o << 7) + (((g ^ (o & 15)) << 3) + j)] = f2bfu(v);
}

// ---------------- MFMA NNConv message GEMM + scatter ----------------
// Double-buffered LDS B, ONE barrier per slab, prefetch overlapped with MFMA.
// msg[e,o] = sum_s x[e,s] * ( He[e,:].e2W[s*64+o,:] + e2b[s*64+o] ), He in A-regs.
// block: 128 edges x 32 slabs (sq = blockIdx&1); 4 waves, wave: M=32 x N=64.
__global__ __launch_bounds__(256) void k_convm(const float* __restrict__ node,
                                               const float* __restrict__ ea,
                                               const float* __restrict__ e1W,
                                               const float* __restrict__ e1b,
                                               const float* __restrict__ e2b,
                                               const unsigned short* __restrict__ Bhat,
                                               const int* __restrict__ src,
                                               const int* __restrict__ dst,
                                               float* __restrict__ agg) {
    __shared__ __align__(16) float xT[32 * 132];          // xT[s_local][e], 16.9 KB
    __shared__ __align__(16) unsigned short Bs[2][8192];  // double-buffered slab (32 KB)
    __shared__ int dst_s[128];

    const int tid = threadIdx.x;
    const int eb = (blockIdx.x >> 1) * 128;
    const int sq = blockIdx.x & 1;                        // slab half: s in [sq*32, sq*32+32)

    const int lane = tid & 63, w = tid >> 6;
    const int quad = lane >> 4, mrow = lane & 15;
    const int stgOff = w * 2048 + lane * 8;

    {   // xT fill: thread = (edge r = tid>>1, half c2 = tid&1), 16 floats each
        int r = tid >> 1, c2 = tid & 1;
        int s = src[eb + r];
        const float* nr = node + (size_t)s * 64 + sq * 32 + c2 * 16;
#pragma unroll
        for (int j = 0; j < 16; j++) xT[(c2 * 16 + j) * 132 + r] = nr[j];
        if (tid < 128) dst_s[tid] = dst[eb + tid];
    }
    {   // prologue: stage first slab into Bs[0]
        const unsigned short* gB = Bhat + ((sq * 32) << 13) + stgOff;
#pragma unroll
        for (int q = 0; q < 4; q++)
            *(uint4*)(Bs[0] + stgOff + q * 512) = *(const uint4*)(gB + q * 512);
    }

    // A-frags (He, bf16) computed directly into registers; constant across slabs
    bh8 af[2][4];
#pragma unroll
    for (int mt = 0; mt < 2; mt++) {
        int e = eb + w * 32 + mt * 16 + mrow;
        const float* ar = ea + (size_t)e * 4;
        float a0 = ar[0], a1 = ar[1], a2 = ar[2], a3 = ar[3];
#pragma unroll
        for (int t = 0; t < 4; t++) {
            union { bh8 v; unsigned short u[8]; } tmp;
#pragma unroll
            for (int j = 0; j < 8; j++) {
                int c = t * 32 + quad * 8 + j;
                const float* wr = e1W + c * 4;
                float h = e1b[c] + a0 * wr[0] + a1 * wr[1] + a2 * wr[2] + a3 * wr[3];
                tmp.u[j] = f2bfu(fmaxf(h, 0.f));
            }
            af[mt][t] = tmp.v;
        }
    }
    __syncthreads();   // xT, dst_s, Bs[0] visible

    const f32x4 z4 = {0.f, 0.f, 0.f, 0.f};
    f32x4 msg[2][4];
#pragma unroll
    for (int mt = 0; mt < 2; mt++)
#pragma unroll
        for (int nt = 0; nt < 4; nt++) msg[mt][nt] = z4;

    for (int s5 = 0; s5 < 32; s5++) {
        const int s = sq * 32 + s5;
        const int cur = s5 & 1, nxt = cur ^ 1;

        // issue prefetch for NEXT slab (latency hidden behind this slab's MFMA)
        uint4 stg[4];
        if (s5 < 31) {
            const unsigned short* gB = Bhat + ((s + 1) << 13) + stgOff;
#pragma unroll
            for (int q = 0; q < 4; q++) stg[q] = *(const uint4*)(gB + q * 512);
        }
        float bb[4];
#pragma unroll
        for (int nt = 0; nt < 4; nt++) bb[nt] = e2b[(s << 6) + nt * 16 + mrow];

        // MFMA from Bs[cur]
        f32x4 acc[2][4];
#pragma unroll
        for (int t = 0; t < 4; t++) {
            bh8 bf[4];
            const int g = t * 4 + quad;
#pragma unroll
            for (int nt = 0; nt < 4; nt++) {
                const int o = nt * 16 + mrow;
                bf[nt] = *(const bh8*)(const void*)(Bs[cur] + o * 128 + ((g ^ (o & 15)) << 3));
            }
#pragma unroll
            for (int mt = 0; mt < 2; mt++)
#pragma unroll
                for (int nt = 0; nt < 4; nt++)
                    acc[mt][nt] = __builtin_amdgcn_mfma_f32_16x16x32_bf16(
                        af[mt][t], bf[nt], (t == 0) ? z4 : acc[mt][nt], 0, 0, 0);
        }
        // drain: msg += x[e,s] * (C_s + e2b_s)
#pragma unroll
        for (int mt = 0; mt < 2; mt++) {
            f32x4 xv = *(const f32x4*)(const void*)(xT + s5 * 132 + w * 32 + mt * 16 + quad * 4);
#pragma unroll
            for (int nt = 0; nt < 4; nt++)
#pragma unroll
                for (int r = 0; r < 4; r++)
                    msg[mt][nt][r] += xv[r] * (acc[mt][nt][r] + bb[nt]);
        }
        // write next slab into the other buffer; ONE barrier per slab
        if (s5 < 31) {
#pragma unroll
            for (int q = 0; q < 4; q++) *(uint4*)(Bs[nxt] + stgOff + q * 512) = stg[q];
        }
        __syncthreads();
    }

    // scatter partial msg (this block's 32-slab contribution)
#pragma unroll
    for (int mt = 0; mt < 2; mt++)
#pragma unroll
        for (int nt = 0; nt < 4; nt++) {
            const int o = nt * 16 + mrow;
#pragma unroll
            for (int r = 0; r < 4; r++) {
                int e = w * 32 + mt * 16 + quad * 4 + r;
                atomicAdd(agg + (size_t)dst_s[e] * 64 + o, msg[mt][nt][r]);
            }
        }
}

// ---------------- fused m+GRU ----------------
__global__ void k_mgru(const float* agg, const float* cnt, const float* node,
                       const float* rootW, const float* convb,
                       const float* WihT, const float* WhhT,
                       const float* bih, const float* bhh, float* hOut) {
    __shared__ float ms[4][68];
    int g = blockIdx.x * 256 + threadIdx.x;
    int n = g >> 6, d = g & 63, sub = threadIdx.x >> 6;
    const float* hrow = node + (size_t)n * 64;
    {
        float inv = 1.f / fmaxf(cnt[n], 1.f);
        float root = 0.f;
        for (int i = 0; i < 64; i++) root += hrow[i] * rootW[i * 64 + d];
        ms[sub][d] = fmaxf(agg[g] * inv + convb[d] + root, 0.f);
    }
    __syncthreads();
    float ir = bih[d], iz = bih[64 + d], in_ = bih[128 + d];
    float hr = bhh[d], hz = bhh[64 + d], hn = bhh[128 + d];
    const float* mr = ms[sub];
    for (int i = 0; i < 64; i++) {
        float mi = mr[i], hi = hrow[i];
        ir += mi * WihT[i * 192 + d];
        iz += mi * WihT[i * 192 + 64 + d];
        in_ += mi * WihT[i * 192 + 128 + d];
        hr += hi * WhhT[i * 192 + d];
        hz += hi * WhhT[i * 192 + 64 + d];
        hn += hi * WhhT[i * 192 + 128 + d];
    }
    float r = sigm(ir + hr);
    float z = sigm(iz + hz);
    float nn = tanhf(in_ + r * hn);
    hOut[g] = (1.f - z) * nn + z * hrow[d];
}

// ---------------- Set2Set LSTM cell; WihT2 [128,256], WhhT2 [64,256] ----------------
__global__ void k_lstm(const float* qstar, const float* hlIn,
                       const float* WihT2, const float* WhhT2,
                       const float* bih, const float* bhh,
                       float* cl, float* hlOut) {
    int g = blockIdx.x * 256 + threadIdx.x;   // b*64+d
    int b = g >> 6, d = g & 63;
    const float* qv = qstar + (size_t)b * 128;
    const float* hr = hlIn + (size_t)b * 64;
    float gate[4];
    for (int gg = 0; gg < 4; gg++) {
        int row = gg * 64 + d;
        float acc = bih[row] + bhh[row];
        for (int j = 0; j < 128; j++) acc += qv[j] * WihT2[j * 256 + row];
        for (int j = 0; j < 64; j++) acc += hr[j] * WhhT2[j * 256 + row];
        gate[gg] = acc;
    }
    float i_ = sigm(gate[0]), f_ = sigm(gate[1]);
    float g_ = tanhf(gate[2]), o_ = sigm(gate[3]);
    float c = f_ * cl[g] + i_ * g_;
    cl[g] = c;
    hlOut[g] = o_ * tanhf(c);
}

// ---------------- e[n] = dot(node[n], q[batch[n]]) ----------------
__global__ void k_escore(const float* node, const float* q, const int* batch, float* e) {
    int tid = threadIdx.x;
    int n = blockIdx.x * 4 + (tid >> 6);
    int lane = tid & 63;
    int b = batch[n];
    float p = node[(size_t)n * 64 + lane] * q[(size_t)b * 64 + lane];
    for (int o = 32; o > 0; o >>= 1) p += __shfl_xor(p, o);
    if (lane == 0) e[n] = p;
}

// ---------------- segment softmax + weighted readout, one wave per graph ----------------
__global__ void k_pool(const float* node, const float* e, const int* batch,
                       const float* q, float* qstar) {
    int b = blockIdx.x; int lane = threadIdx.x;  // 64 threads
    int lo = 0, hi = NN_;
    while (lo < hi) { int mid = (lo + hi) >> 1; if (batch[mid] < b) lo = mid + 1; else hi = mid; }
    int start = lo;
    lo = start; hi = NN_;
    while (lo < hi) { int mid = (lo + hi) >> 1; if (batch[mid] < b + 1) lo = mid + 1; else hi = mid; }
    int end = lo;
    float r = 0.f;
    if (end > start) {
        float mx = -1e30f;
        for (int n = start + lane; n < end; n += 64) mx = fmaxf(mx, e[n]);
        for (int o = 32; o > 0; o >>= 1) mx = fmaxf(mx, __shfl_xor(mx, o));
        float den = 0.f;
        for (int n = start + lane; n < end; n += 64) den += expf(e[n] - mx);
        for (int o = 32; o > 0; o >>= 1) den += __shfl_xor(den, o);
        float inv = 1.f / den;
        for (int n = start; n < end; n++) {
            float wgt = expf(e[n] - mx) * inv;
            r += wgt * node[(size_t)n * 64 + lane];
        }
    }
    qstar[(size_t)b * 128 + lane] = q[(size_t)b * 64 + lane];
    qstar[(size_t)b * 128 + 64 + lane] = r;
}

// ---------------- head ----------------
__global__ void k_fc(const float* qstar, const float* W1, const float* b1,
                     const float* W2, const float* b2, float* out) {
    __shared__ float hid[128];
    int b = blockIdx.x; int t = threadIdx.x;  // 128 threads
    const float* qr = qstar + (size_t)b * 128;
    float acc = b1[t];
    const float* wr = W1 + (size_t)t * 128;
    for (int k = 0; k < 128; k++) acc += qr[k] * wr[k];
    hid[t] = fmaxf(acc, 0.f);
    __syncthreads();
    if (t < 64) {
        float s = hid[t] * W2[t] + hid[t + 64] * W2[t + 64];
        for (int o = 32; o > 0; o >>= 1) s += __shfl_xor(s, o);
        if (t == 0) out[b] = s + b2[0];
    }
}

extern "C" void kernel_launch(void* const* d_in, const int* in_sizes, int n_in,
                              void* d_out, int out_size, void* d_ws, size_t ws_size,
                              hipStream_t stream) {
    const float* x     = (const float*)d_in[0];
    const int*   ei    = (const int*)d_in[1];
    const float* ea    = (const float*)d_in[2];
    const int*   batch = (const int*)d_in[3];
    const float* lin0W = (const float*)d_in[4];
    const float* lin0b = (const float*)d_in[5];
    const float* e1W   = (const float*)d_in[6];
    const float* e1b   = (const float*)d_in[7];
    const float* e2W   = (const float*)d_in[8];
    const float* e2b   = (const float*)d_in[9];
    const float* rootW = (const float*)d_in[10];
    const float* convb = (const float*)d_in[11];
    const float* gWih  = (const float*)d_in[12];
    const float* gWhh  = (const float*)d_in[13];
    const float* gbih  = (const float*)d_in[14];
    const float* gbhh  = (const float*)d_in[15];
    const float* lWih  = (const float*)d_in[16];
    const float* lWhh  = (const float*)d_in[17];
    const float* lbih  = (const float*)d_in[18];
    const float* lbhh  = (const float*)d_in[19];
    const float* fc1W  = (const float*)d_in[20];
    const float* fc1b  = (const float*)d_in[21];
    const float* fc2W  = (const float*)d_in[22];
    const float* fc2b  = (const float*)d_in[23];
    const int* src = ei;
    const int* dst = ei + NE_;

    // workspace carve (~28 MB)
    char* p = (char*)d_ws;
    auto alloc = [&](size_t bytes) -> char* {
        char* r = p; p += (bytes + 255) & ~(size_t)255; return r;
    };
    unsigned short* Bhat = (unsigned short*)alloc((size_t)64 * 8192 * 2);
    float* nodeA  = (float*)alloc((size_t)NN_ * 64 * 4);
    float* nodeB  = (float*)alloc((size_t)NN_ * 64 * 4);
    float* aggb   = (float*)alloc((size_t)NN_ * 64 * 4);
    float* cnt    = (float*)alloc((size_t)NN_ * 4);
    float* ebuf   = (float*)alloc((size_t)NN_ * 4);
    float* WihT   = (float*)alloc(192 * 64 * 4);
    float* WhhT   = (float*)alloc(192 * 64 * 4);
    float* WihT2  = (float*)alloc(256 * 128 * 4);
    float* WhhT2  = (float*)alloc(256 * 64 * 4);
    float* qstar  = (float*)alloc((size_t)NG_ * 128 * 4);  // qstar,hlA,hlB,clb contiguous
    float* hlA    = (float*)alloc((size_t)NG_ * 64 * 4);
    float* hlB    = (float*)alloc((size_t)NG_ * 64 * 4);
    float* clb    = (float*)alloc((size_t)NG_ * 64 * 4);

    k_zero<<<(NN_ + 255) / 256, 256, 0, stream>>>(cnt, NN_);
    k_zero<<<(NG_ * 320 + 255) / 256, 256, 0, stream>>>(qstar, NG_ * 320);
    k_lin0<<<NN_ * 64 / 256, 256, 0, stream>>>(x, lin0W, lin0b, nodeA);
    k_cnt<<<NE_ / 256, 256, 0, stream>>>(dst, cnt);
    k_t192<<<48, 256, 0, stream>>>(gWih, WihT);
    k_t192<<<48, 256, 0, stream>>>(gWhh, WhhT);
    k_tlih<<<128, 256, 0, stream>>>(lWih, WihT2);
    k_tlhh<<<64, 256, 0, stream>>>(lWhh, WhhT2);
    k_bhat<<<64 * 8192 / 256, 256, 0, stream>>>(e2W, Bhat);

    float* curF = nodeA; float* nxtF = nodeB;
    for (int it = 0; it < 3; it++) {
        k_zero<<<NN_ * 64 / 256, 256, 0, stream>>>(aggb, NN_ * 64);
        k_convm<<<(NE_ / 128) * 2, 256, 0, stream>>>(curF, ea, e1W, e1b, e2b, Bhat, src, dst, aggb);
        k_mgru<<<NN_ * 64 / 256, 256, 0, stream>>>(aggb, cnt, curF, rootW, convb,
                                                   WihT, WhhT, gbih, gbhh, nxtF);
        float* tf = curF; curF = nxtF; nxtF = tf;
    }

    float* hcur = hlA; float* hnxt = hlB;
    for (int s = 0; s < 3; s++) {
        k_lstm<<<NG_ * 64 / 256, 256, 0, stream>>>(qstar, hcur, WihT2, WhhT2, lbih, lbhh, clb, hnxt);
        k_escore<<<NN_ / 4, 256, 0, stream>>>(curF, hnxt, batch, ebuf);
        k_pool<<<NG_, 64, 0, stream>>>(curF, ebuf, batch, hnxt, qstar);
        float* t = hcur; hcur = hnxt; hnxt = t;
    }
    k_fc<<<NG_, 128, 0, stream>>>(qstar, fc1W, fc1b, fc2W, fc2b, (float*)d_out);
}

// Round 14
// 630.298 us; speedup vs baseline: 16.8720x; 1.3426x over previous
//
#include <hip/hip_runtime.h>
#include <math.h>

#define NN_ 32768      // nodes
#define NE_ 49152      // edges
#define NG_ 1024       // graphs

typedef short bh8 __attribute__((ext_vector_type(8)));   // 8 bf16 bit-patterns (4 VGPR)
typedef float f32x4 __attribute__((ext_vector_type(4)));

__device__ __forceinline__ unsigned short f2bfu(float f) {   // RNE float->bf16 bits
    union { float f; unsigned int i; } x; x.f = f;
    unsigned int u = x.i;
    u += 0x7FFFu + ((u >> 16) & 1u);
    return (unsigned short)(u >> 16);
}
__device__ __forceinline__ float sigm(float x) { return 1.f / (1.f + expf(-x)); }

// Kept for harness compatibility (unused).
__global__ void MPNN_78632261256134_kernel() {}

// ---------------- zero fill ----------------
__global__ void k_zero(float* p, int n) {
    int i = blockIdx.x * 256 + threadIdx.x;
    if (i < n) p[i] = 0.f;
}

// ---------------- lin0 ----------------
__global__ void k_lin0(const float* x, const float* W, const float* b, float* node) {
    int g = blockIdx.x * 256 + threadIdx.x;   // n*64+d
    int n = g >> 6, d = g & 63;
    const float* xr = x + n * 14;
    const float* wr = W + d * 14;
    float acc = b[d];
    for (int i = 0; i < 14; i++) acc += xr[i] * wr[i];
    node[g] = fmaxf(acc, 0.f);
}

// ---------------- in-degree count ----------------
__global__ void k_cnt(const int* dst, float* cnt) {
    int e = blockIdx.x * 256 + threadIdx.x;
    if (e < NE_) atomicAdd(&cnt[dst[e]], 1.0f);
}

// ---------------- transposes (coalesced weight reads) ----------------
__global__ void k_t192(const float* Win, float* Wout) {   // [192,64] -> [64,192]
    int t = blockIdx.x * 256 + threadIdx.x;
    if (t < 192 * 64) { int gr = t >> 6, i = t & 63; Wout[i * 192 + gr] = Win[gr * 64 + i]; }
}
__global__ void k_tlih(const float* Win, float* Wout) {   // [256,128] -> [128,256]
    int t = blockIdx.x * 256 + threadIdx.x;
    if (t < 256 * 128) { int r = t >> 7, c = t & 127; Wout[c * 256 + r] = Win[t]; }
}
__global__ void k_tlhh(const float* Win, float* Wout) {   // [256,64] -> [64,256]
    int t = blockIdx.x * 256 + threadIdx.x;
    if (t < 256 * 64) { int r = t >> 6, c = t & 63; Wout[c * 256 + r] = Win[t]; }
}

// ---------------- Bhat: bf16 [64 slabs][64 o][128 k], granule-XOR swizzled ----------------
__global__ void k_bhat(const float* e2W, unsigned short* Bhat) {
    int idx = blockIdx.x * 256 + threadIdx.x;   // < 64*8192
    if (idx >= 64 * 8192) return;
    int s = idx >> 13, r = idx & 8191, o = r >> 7, k = r & 127;
    float v = e2W[idx];
    int g = k >> 3, j = k & 7;
    Bhat[(s << 13) + (o << 7) + (((g ^ (o & 15)) << 3) + j)] = f2bfu(v);
}

// ---------------- MFMA NNConv message GEMM + scatter ----------------
// Double-buffered LDS B, ONE barrier per slab, prefetch overlapped with MFMA.
// block: 128 edges x 32 slabs (sq = blockIdx&1); 4 waves, wave: M=32 x N=64.
__global__ __launch_bounds__(256) void k_convm(const float* __restrict__ node,
                                               const float* __restrict__ ea,
                                               const float* __restrict__ e1W,
                                               const float* __restrict__ e1b,
                                               const float* __restrict__ e2b,
                                               const unsigned short* __restrict__ Bhat,
                                               const int* __restrict__ src,
                                               const int* __restrict__ dst,
                                               float* __restrict__ agg) {
    __shared__ __align__(16) float xT[32 * 132];          // xT[s_local][e], 16.9 KB
    __shared__ __align__(16) unsigned short Bs[2][8192];  // double-buffered slab (32 KB)
    __shared__ int dst_s[128];

    const int tid = threadIdx.x;
    const int eb = (blockIdx.x >> 1) * 128;
    const int sq = blockIdx.x & 1;                        // slab half: s in [sq*32, sq*32+32)

    const int lane = tid & 63, w = tid >> 6;
    const int quad = lane >> 4, mrow = lane & 15;
    const int stgOff = w * 2048 + lane * 8;

    {   // xT fill: thread = (edge r = tid>>1, half c2 = tid&1), 16 floats each
        int r = tid >> 1, c2 = tid & 1;
        int s = src[eb + r];
        const float* nr = node + (size_t)s * 64 + sq * 32 + c2 * 16;
#pragma unroll
        for (int j = 0; j < 16; j++) xT[(c2 * 16 + j) * 132 + r] = nr[j];
        if (tid < 128) dst_s[tid] = dst[eb + tid];
    }
    {   // prologue: stage first slab into Bs[0]
        const unsigned short* gB = Bhat + ((sq * 32) << 13) + stgOff;
#pragma unroll
        for (int q = 0; q < 4; q++)
            *(uint4*)(Bs[0] + stgOff + q * 512) = *(const uint4*)(gB + q * 512);
    }

    // A-frags (He, bf16) computed directly into registers; constant across slabs
    bh8 af[2][4];
#pragma unroll
    for (int mt = 0; mt < 2; mt++) {
        int e = eb + w * 32 + mt * 16 + mrow;
        const float* ar = ea + (size_t)e * 4;
        float a0 = ar[0], a1 = ar[1], a2 = ar[2], a3 = ar[3];
#pragma unroll
        for (int t = 0; t < 4; t++) {
            union { bh8 v; unsigned short u[8]; } tmp;
#pragma unroll
            for (int j = 0; j < 8; j++) {
                int c = t * 32 + quad * 8 + j;
                const float* wr = e1W + c * 4;
                float h = e1b[c] + a0 * wr[0] + a1 * wr[1] + a2 * wr[2] + a3 * wr[3];
                tmp.u[j] = f2bfu(fmaxf(h, 0.f));
            }
            af[mt][t] = tmp.v;
        }
    }
    __syncthreads();   // xT, dst_s, Bs[0] visible

    const f32x4 z4 = {0.f, 0.f, 0.f, 0.f};
    f32x4 msg[2][4];
#pragma unroll
    for (int mt = 0; mt < 2; mt++)
#pragma unroll
        for (int nt = 0; nt < 4; nt++) msg[mt][nt] = z4;

    for (int s5 = 0; s5 < 32; s5++) {
        const int s = sq * 32 + s5;
        const int cur = s5 & 1, nxt = cur ^ 1;

        uint4 stg[4];
        if (s5 < 31) {
            const unsigned short* gB = Bhat + ((s + 1) << 13) + stgOff;
#pragma unroll
            for (int q = 0; q < 4; q++) stg[q] = *(const uint4*)(gB + q * 512);
        }
        float bb[4];
#pragma unroll
        for (int nt = 0; nt < 4; nt++) bb[nt] = e2b[(s << 6) + nt * 16 + mrow];

        f32x4 acc[2][4];
#pragma unroll
        for (int t = 0; t < 4; t++) {
            bh8 bf[4];
            const int g = t * 4 + quad;
#pragma unroll
            for (int nt = 0; nt < 4; nt++) {
                const int o = nt * 16 + mrow;
                bf[nt] = *(const bh8*)(const void*)(Bs[cur] + o * 128 + ((g ^ (o & 15)) << 3));
            }
#pragma unroll
            for (int mt = 0; mt < 2; mt++)
#pragma unroll
                for (int nt = 0; nt < 4; nt++)
                    acc[mt][nt] = __builtin_amdgcn_mfma_f32_16x16x32_bf16(
                        af[mt][t], bf[nt], (t == 0) ? z4 : acc[mt][nt], 0, 0, 0);
        }
#pragma unroll
        for (int mt = 0; mt < 2; mt++) {
            f32x4 xv = *(const f32x4*)(const void*)(xT + s5 * 132 + w * 32 + mt * 16 + quad * 4);
#pragma unroll
            for (int nt = 0; nt < 4; nt++)
#pragma unroll
                for (int r = 0; r < 4; r++)
                    msg[mt][nt][r] += xv[r] * (acc[mt][nt][r] + bb[nt]);
        }
        if (s5 < 31) {
#pragma unroll
            for (int q = 0; q < 4; q++) *(uint4*)(Bs[nxt] + stgOff + q * 512) = stg[q];
        }
        __syncthreads();
    }

#pragma unroll
    for (int mt = 0; mt < 2; mt++)
#pragma unroll
        for (int nt = 0; nt < 4; nt++) {
            const int o = nt * 16 + mrow;
#pragma unroll
            for (int r = 0; r < 4; r++) {
                int e = w * 32 + mt * 16 + quad * 4 + r;
                atomicAdd(agg + (size_t)dst_s[e] * 64 + o, msg[mt][nt][r]);
            }
        }
}

// ---------------- fused m+GRU, 16 nodes/block, 4 nodes/thread (weight reuse x4) ------------
// thread (sub = tid>>6, d = tid&63) handles nodes nb + sub*4 + {0..3} at dim d.
__global__ __launch_bounds__(256) void k_mgru(const float* __restrict__ agg,
                                              const float* __restrict__ cnt,
                                              const float* __restrict__ node,
                                              const float* __restrict__ rootW,
                                              const float* __restrict__ convb,
                                              const float* __restrict__ WihT,
                                              const float* __restrict__ WhhT,
                                              const float* __restrict__ bih,
                                              const float* __restrict__ bhh,
                                              float* __restrict__ hOut) {
    __shared__ float hs[16][68];
    __shared__ float ms[16][68];
    const int tid = threadIdx.x;
    const int d = tid & 63, sub = tid >> 6;
    const int nb = blockIdx.x * 16;
    const int r0 = sub * 4;

    // stage h rows (coalesced)
#pragma unroll
    for (int j = 0; j < 4; j++)
        hs[r0 + j][d] = node[(size_t)(nb + r0 + j) * 64 + d];
    __syncthreads();

    // m = relu(agg/cnt + h@rootW + convb), rootW row-load shared across 4 nodes
    {
        float root[4] = {0.f, 0.f, 0.f, 0.f};
        for (int i = 0; i < 64; i++) {
            float wv = rootW[i * 64 + d];
#pragma unroll
            for (int j = 0; j < 4; j++) root[j] += hs[r0 + j][i] * wv;
        }
        float cb = convb[d];
#pragma unroll
        for (int j = 0; j < 4; j++) {
            int n = nb + r0 + j;
            float inv = 1.f / fmaxf(cnt[n], 1.f);
            ms[r0 + j][d] = fmaxf(agg[(size_t)n * 64 + d] * inv + cb + root[j], 0.f);
        }
    }
    __syncthreads();

    // GRU: 6 weight loads per i shared across 4 nodes
    float ir[4], iz[4], in_[4], hr[4], hz[4], hn[4];
    {
        float bi0 = bih[d], bi1 = bih[64 + d], bi2 = bih[128 + d];
        float bh0 = bhh[d], bh1 = bhh[64 + d], bh2 = bhh[128 + d];
#pragma unroll
        for (int j = 0; j < 4; j++) {
            ir[j] = bi0; iz[j] = bi1; in_[j] = bi2;
            hr[j] = bh0; hz[j] = bh1; hn[j] = bh2;
        }
    }
    for (int i = 0; i < 64; i++) {
        float wi0 = WihT[i * 192 + d];
        float wi1 = WihT[i * 192 + 64 + d];
        float wi2 = WihT[i * 192 + 128 + d];
        float wh0 = WhhT[i * 192 + d];
        float wh1 = WhhT[i * 192 + 64 + d];
        float wh2 = WhhT[i * 192 + 128 + d];
#pragma unroll
        for (int j = 0; j < 4; j++) {
            float mi = ms[r0 + j][i], hi = hs[r0 + j][i];
            ir[j] += mi * wi0; iz[j] += mi * wi1; in_[j] += mi * wi2;
            hr[j] += hi * wh0; hz[j] += hi * wh1; hn[j] += hi * wh2;
        }
    }
#pragma unroll
    for (int j = 0; j < 4; j++) {
        float r = sigm(ir[j] + hr[j]);
        float z = sigm(iz[j] + hz[j]);
        float nn = tanhf(in_[j] + r * hn[j]);
        hOut[(size_t)(nb + r0 + j) * 64 + d] = (1.f - z) * nn + z * hs[r0 + j][d];
    }
}

// ---------------- Set2Set LSTM cell; WihT2 [128,256], WhhT2 [64,256] ----------------
__global__ void k_lstm(const float* qstar, const float* hlIn,
                       const float* WihT2, const float* WhhT2,
                       const float* bih, const float* bhh,
                       float* cl, float* hlOut) {
    int g = blockIdx.x * 256 + threadIdx.x;   // b*64+d
    int b = g >> 6, d = g & 63;
    const float* qv = qstar + (size_t)b * 128;
    const float* hr = hlIn + (size_t)b * 64;
    float gate[4];
    for (int gg = 0; gg < 4; gg++) {
        int row = gg * 64 + d;
        float acc = bih[row] + bhh[row];
        for (int j = 0; j < 128; j++) acc += qv[j] * WihT2[j * 256 + row];
        for (int j = 0; j < 64; j++) acc += hr[j] * WhhT2[j * 256 + row];
        gate[gg] = acc;
    }
    float i_ = sigm(gate[0]), f_ = sigm(gate[1]);
    float g_ = tanhf(gate[2]), o_ = sigm(gate[3]);
    float c = f_ * cl[g] + i_ * g_;
    cl[g] = c;
    hlOut[g] = o_ * tanhf(c);
}

// ---------------- e[n] = dot(node[n], q[batch[n]]) ----------------
__global__ void k_escore(const float* node, const float* q, const int* batch, float* e) {
    int tid = threadIdx.x;
    int n = blockIdx.x * 4 + (tid >> 6);
    int lane = tid & 63;
    int b = batch[n];
    float p = node[(size_t)n * 64 + lane] * q[(size_t)b * 64 + lane];
    for (int o = 32; o > 0; o >>= 1) p += __shfl_xor(p, o);
    if (lane == 0) e[n] = p;
}

// ---------------- segment softmax + weighted readout, one wave per graph ----------------
__global__ void k_pool(const float* node, const float* e, const int* batch,
                       const float* q, float* qstar) {
    int b = blockIdx.x; int lane = threadIdx.x;  // 64 threads
    int lo = 0, hi = NN_;
    while (lo < hi) { int mid = (lo + hi) >> 1; if (batch[mid] < b) lo = mid + 1; else hi = mid; }
    int start = lo;
    lo = start; hi = NN_;
    while (lo < hi) { int mid = (lo + hi) >> 1; if (batch[mid] < b + 1) lo = mid + 1; else hi = mid; }
    int end = lo;
    float r = 0.f;
    if (end > start) {
        float mx = -1e30f;
        for (int n = start + lane; n < end; n += 64) mx = fmaxf(mx, e[n]);
        for (int o = 32; o > 0; o >>= 1) mx = fmaxf(mx, __shfl_xor(mx, o));
        float den = 0.f;
        for (int n = start + lane; n < end; n += 64) den += expf(e[n] - mx);
        for (int o = 32; o > 0; o >>= 1) den += __shfl_xor(den, o);
        float inv = 1.f / den;
        for (int n = start; n < end; n++) {
            float wgt = expf(e[n] - mx) * inv;
            r += wgt * node[(size_t)n * 64 + lane];
        }
    }
    qstar[(size_t)b * 128 + lane] = q[(size_t)b * 64 + lane];
    qstar[(size_t)b * 128 + 64 + lane] = r;
}

// ---------------- head ----------------
__global__ void k_fc(const float* qstar, const float* W1, const float* b1,
                     const float* W2, const float* b2, float* out) {
    __shared__ float hid[128];
    int b = blockIdx.x; int t = threadIdx.x;  // 128 threads
    const float* qr = qstar + (size_t)b * 128;
    float acc = b1[t];
    const float* wr = W1 + (size_t)t * 128;
    for (int k = 0; k < 128; k++) acc += qr[k] * wr[k];
    hid[t] = fmaxf(acc, 0.f);
    __syncthreads();
    if (t < 64) {
        float s = hid[t] * W2[t] + hid[t + 64] * W2[t + 64];
        for (int o = 32; o > 0; o >>= 1) s += __shfl_xor(s, o);
        if (t == 0) out[b] = s + b2[0];
    }
}

extern "C" void kernel_launch(void* const* d_in, const int* in_sizes, int n_in,
                              void* d_out, int out_size, void* d_ws, size_t ws_size,
                              hipStream_t stream) {
    const float* x     = (const float*)d_in[0];
    const int*   ei    = (const int*)d_in[1];
    const float* ea    = (const float*)d_in[2];
    const int*   batch = (const int*)d_in[3];
    const float* lin0W = (const float*)d_in[4];
    const float* lin0b = (const float*)d_in[5];
    const float* e1W   = (const float*)d_in[6];
    const float* e1b   = (const float*)d_in[7];
    const float* e2W   = (const float*)d_in[8];
    const float* e2b   = (const float*)d_in[9];
    const float* rootW = (const float*)d_in[10];
    const float* convb = (const float*)d_in[11];
    const float* gWih  = (const float*)d_in[12];
    const float* gWhh  = (const float*)d_in[13];
    const float* gbih  = (const float*)d_in[14];
    const float* gbhh  = (const float*)d_in[15];
    const float* lWih  = (const float*)d_in[16];
    const float* lWhh  = (const float*)d_in[17];
    const float* lbih  = (const float*)d_in[18];
    const float* lbhh  = (const float*)d_in[19];
    const float* fc1W  = (const float*)d_in[20];
    const float* fc1b  = (const float*)d_in[21];
    const float* fc2W  = (const float*)d_in[22];
    const float* fc2b  = (const float*)d_in[23];
    const int* src = ei;
    const int* dst = ei + NE_;

    // workspace carve (~28 MB)
    char* p = (char*)d_ws;
    auto alloc = [&](size_t bytes) -> char* {
        char* r = p; p += (bytes + 255) & ~(size_t)255; return r;
    };
    unsigned short* Bhat = (unsigned short*)alloc((size_t)64 * 8192 * 2);
    float* nodeA  = (float*)alloc((size_t)NN_ * 64 * 4);
    float* nodeB  = (float*)alloc((size_t)NN_ * 64 * 4);
    float* aggb   = (float*)alloc((size_t)NN_ * 64 * 4);
    float* cnt    = (float*)alloc((size_t)NN_ * 4);
    float* ebuf   = (float*)alloc((size_t)NN_ * 4);
    float* WihT   = (float*)alloc(192 * 64 * 4);
    float* WhhT   = (float*)alloc(192 * 64 * 4);
    float* WihT2  = (float*)alloc(256 * 128 * 4);
    float* WhhT2  = (float*)alloc(256 * 64 * 4);
    float* qstar  = (float*)alloc((size_t)NG_ * 128 * 4);  // qstar,hlA,hlB,clb contiguous
    float* hlA    = (float*)alloc((size_t)NG_ * 64 * 4);
    float* hlB    = (float*)alloc((size_t)NG_ * 64 * 4);
    float* clb    = (float*)alloc((size_t)NG_ * 64 * 4);

    k_zero<<<(NN_ + 255) / 256, 256, 0, stream>>>(cnt, NN_);
    k_zero<<<(NG_ * 320 + 255) / 256, 256, 0, stream>>>(qstar, NG_ * 320);
    k_lin0<<<NN_ * 64 / 256, 256, 0, stream>>>(x, lin0W, lin0b, nodeA);
    k_cnt<<<NE_ / 256, 256, 0, stream>>>(dst, cnt);
    k_t192<<<48, 256, 0, stream>>>(gWih, WihT);
    k_t192<<<48, 256, 0, stream>>>(gWhh, WhhT);
    k_tlih<<<128, 256, 0, stream>>>(lWih, WihT2);
    k_tlhh<<<64, 256, 0, stream>>>(lWhh, WhhT2);
    k_bhat<<<64 * 8192 / 256, 256, 0, stream>>>(e2W, Bhat);

    float* curF = nodeA; float* nxtF = nodeB;
    for (int it = 0; it < 3; it++) {
        k_zero<<<NN_ * 64 / 256, 256, 0, stream>>>(aggb, NN_ * 64);
        k_convm<<<(NE_ / 128) * 2, 256, 0, stream>>>(curF, ea, e1W, e1b, e2b, Bhat, src, dst, aggb);
        k_mgru<<<NN_ / 16, 256, 0, stream>>>(aggb, cnt, curF, rootW, convb,
                                             WihT, WhhT, gbih, gbhh, nxtF);
        float* tf = curF; curF = nxtF; nxtF = tf;
    }

    float* hcur = hlA; float* hnxt = hlB;
    for (int s = 0; s < 3; s++) {
        k_lstm<<<NG_ * 64 / 256, 256, 0, stream>>>(qstar, hcur, WihT2, WhhT2, lbih, lbhh, clb, hnxt);
        k_escore<<<NN_ / 4, 256, 0, stream>>>(curF, hnxt, batch, ebuf);
        k_pool<<<NG_, 64, 0, stream>>>(curF, ebuf, batch, hnxt, qstar);
        float* t = hcur; hcur = hnxt; hnxt = t;
    }
    k_fc<<<NG_, 128, 0, stream>>>(qstar, fc1W, fc1b, fc2W, fc2b, (float*)d_out);
}

// Round 16
// 608.842 us; speedup vs baseline: 17.4666x; 1.0352x over previous
//
#include <hip/hip_runtime.h>
#include <math.h>

#define NN_ 32768      // nodes
#define NE_ 49152      // edges
#define NG_ 1024       // graphs

typedef short bh8 __attribute__((ext_vector_type(8)));   // 8 bf16 bit-patterns (4 VGPR)
typedef float f32x4 __attribute__((ext_vector_type(4)));

__device__ __forceinline__ unsigned short f2bfu(float f) {   // RNE float->bf16 bits
    union { float f; unsigned int i; } x; x.f = f;
    unsigned int u = x.i;
    u += 0x7FFFu + ((u >> 16) & 1u);
    return (unsigned short)(u >> 16);
}
__device__ __forceinline__ float sigm(float x) { return 1.f / (1.f + expf(-x)); }

// Kept for harness compatibility (unused).
__global__ void MPNN_78632261256134_kernel() {}

// ---------------- zero fill ----------------
__global__ void k_zero(float* p, int n) {
    int i = blockIdx.x * 256 + threadIdx.x;
    if (i < n) p[i] = 0.f;
}

// ---------------- lin0 ----------------
__global__ void k_lin0(const float* x, const float* W, const float* b, float* node) {
    int g = blockIdx.x * 256 + threadIdx.x;   // n*64+d
    int n = g >> 6, d = g & 63;
    const float* xr = x + n * 14;
    const float* wr = W + d * 14;
    float acc = b[d];
    for (int i = 0; i < 14; i++) acc += xr[i] * wr[i];
    node[g] = fmaxf(acc, 0.f);
}

// ---------------- in-degree count ----------------
__global__ void k_cnt(const int* dst, float* cnt) {
    int e = blockIdx.x * 256 + threadIdx.x;
    if (e < NE_) atomicAdd(&cnt[dst[e]], 1.0f);
}

// ---------------- transposes (coalesced weight reads) ----------------
__global__ void k_t192(const float* Win, float* Wout) {   // [192,64] -> [64,192]
    int t = blockIdx.x * 256 + threadIdx.x;
    if (t < 192 * 64) { int gr = t >> 6, i = t & 63; Wout[i * 192 + gr] = Win[gr * 64 + i]; }
}
__global__ void k_tlih(const float* Win, float* Wout) {   // [256,128] -> [128,256]
    int t = blockIdx.x * 256 + threadIdx.x;
    if (t < 256 * 128) { int r = t >> 7, c = t & 127; Wout[c * 256 + r] = Win[t]; }
}
__global__ void k_tlhh(const float* Win, float* Wout) {   // [256,64] -> [64,256]
    int t = blockIdx.x * 256 + threadIdx.x;
    if (t < 256 * 64) { int r = t >> 6, c = t & 63; Wout[c * 256 + r] = Win[t]; }
}

// ---------------- Bhat3: frag-contiguous bf16 B [s][w][t][lane][8] ----------------
// Bhat3[(((s*4+w)*4+t)*64+lane)*8+j] = bf16(e2W[(s*64+w*16+(lane&15))*128 + t*32+(lane>>4)*8+j])
__global__ void k_bhat3(const float* e2W, unsigned short* Bhat3) {
    int idx = blockIdx.x * 256 + threadIdx.x;   // < 524288
    if (idx >= 64 * 4 * 4 * 64 * 8) return;
    int j = idx & 7, lane = (idx >> 3) & 63, t = (idx >> 9) & 3, w = (idx >> 11) & 3, s = idx >> 13;
    int row = s * 64 + w * 16 + (lane & 15);
    int k = t * 32 + (lane >> 4) * 8 + j;
    Bhat3[idx] = f2bfu(e2W[row * 128 + k]);
}

// ---------------- Hhat: frag-ready He (iteration-invariant, computed once) ----------------
// gi = etile*4+t; Hhat[gi*512 + lane*8 + j] = bf16(relu(ea[e]@e1W^T+e1b)[c]),
// e = etile*16+(lane&15), c = t*32+(lane>>4)*8+j.  Grid must cover gi < (NE_/16)*4.
__global__ __launch_bounds__(256) void k_he(const float* __restrict__ ea,
                                            const float* __restrict__ e1W,
                                            const float* __restrict__ e1b,
                                            unsigned short* __restrict__ Hhat) {
    int tid = threadIdx.x;
    int lane = tid & 63, sub = tid >> 6;
    int gi = blockIdx.x * 4 + sub;            // < (NE_/16)*4 = 12288
    int etile = gi >> 2, t = gi & 3;
    int e = etile * 16 + (lane & 15), quad = lane >> 4;
    const float* ar = ea + (size_t)e * 4;
    float a0 = ar[0], a1 = ar[1], a2 = ar[2], a3 = ar[3];
    union { unsigned short u[8]; uint4 q; } o;
#pragma unroll
    for (int j = 0; j < 8; j++) {
        int c = t * 32 + quad * 8 + j;
        const float* wr = e1W + c * 4;
        float h = e1b[c] + a0 * wr[0] + a1 * wr[1] + a2 * wr[2] + a3 * wr[3];
        o.u[j] = f2bfu(fmaxf(h, 0.f));
    }
    *(uint4*)(Hhat + (size_t)gi * 512 + lane * 8) = o.q;
}

// ---------------- MFMA NNConv, register-direct B, NO barriers in K-loop ----------------
// block = 64 edges; 4 waves = disjoint col-quarters (w*16..+15); wave M=64 x N=16.
// msg[e,o] = sum_s x[e,s] * ( He[e,:].e2W[s*64+o,:] + e2b[s*64+o] )
__global__ __launch_bounds__(256) void k_convr(const float* __restrict__ node,
                                               const unsigned short* __restrict__ Hhat,
                                               const unsigned short* __restrict__ Bhat3,
                                               const float* __restrict__ e2b,
                                               const int* __restrict__ src,
                                               const int* __restrict__ dst,
                                               float* __restrict__ agg) {
    __shared__ __align__(16) float xs[64 * 68];   // xs[s][e], stride 68 (272B = 17*16)
    __shared__ int dst_s[64];

    const int tid = threadIdx.x;
    const int eb = blockIdx.x * 64;
    const int lane = tid & 63, w = tid >> 6;
    const int quad = lane >> 4, mrow = lane & 15;

    {   // stage x^T: thread = (edge r = tid>>2, dim-group c = tid&3), 16 floats
        int r = tid >> 2, c = tid & 3;
        int s = src[eb + r];
        const float* nr = node + (size_t)s * 64 + c * 16;
#pragma unroll
        for (int j = 0; j < 16; j++) xs[(c * 16 + j) * 68 + r] = nr[j];
        if (tid < 64) dst_s[tid] = dst[eb + tid];
    }

    // A-frags from Hhat (coalesced 16B/lane loads)
    bh8 af[4][4];
#pragma unroll
    for (int mt = 0; mt < 4; mt++)
#pragma unroll
        for (int t = 0; t < 4; t++)
            af[mt][t] = *(const bh8*)(const void*)(
                Hhat + (size_t)(((eb >> 4) + mt) * 4 + t) * 512 + lane * 8);
    __syncthreads();   // xs, dst_s ready — the ONLY barrier

    const f32x4 z4 = {0.f, 0.f, 0.f, 0.f};
    f32x4 msg[4];
#pragma unroll
    for (int mt = 0; mt < 4; mt++) msg[mt] = z4;

    // prefetch slab 0
    bh8 bn[4];
#pragma unroll
    for (int t = 0; t < 4; t++)
        bn[t] = *(const bh8*)(const void*)(Bhat3 + (size_t)((0 * 4 + w) * 4 + t) * 512 + lane * 8);
    float bbn = e2b[w * 16 + mrow];

    for (int s = 0; s < 64; s++) {
        bh8 bc[4];
#pragma unroll
        for (int t = 0; t < 4; t++) bc[t] = bn[t];
        const float bb = bbn;
        if (s < 63) {   // issue next-slab loads; whole MFMA+drain hides the latency
#pragma unroll
            for (int t = 0; t < 4; t++)
                bn[t] = *(const bh8*)(const void*)(
                    Bhat3 + (size_t)(((s + 1) * 4 + w) * 4 + t) * 512 + lane * 8);
            bbn = e2b[(s + 1) * 64 + w * 16 + mrow];
        }

        f32x4 acc[4];
#pragma unroll
        for (int t = 0; t < 4; t++)
#pragma unroll
            for (int mt = 0; mt < 4; mt++)
                acc[mt] = __builtin_amdgcn_mfma_f32_16x16x32_bf16(
                    af[mt][t], bc[t], (t == 0) ? z4 : acc[mt], 0, 0, 0);

        // drain: msg += x[e,s] * (C + e2b)
#pragma unroll
        for (int mt = 0; mt < 4; mt++) {
            f32x4 xv = *(const f32x4*)(const void*)(xs + s * 68 + mt * 16 + quad * 4);
#pragma unroll
            for (int r = 0; r < 4; r++)
                msg[mt][r] += xv[r] * (acc[mt][r] + bb);
        }
    }

    // scatter: edge = eb + mt*16 + quad*4 + r, col = w*16 + mrow
#pragma unroll
    for (int mt = 0; mt < 4; mt++)
#pragma unroll
        for (int r = 0; r < 4; r++)
            atomicAdd(agg + (size_t)dst_s[mt * 16 + quad * 4 + r] * 64 + w * 16 + mrow,
                      msg[mt][r]);
}

// ---------------- fused m+GRU, 16 nodes/block, 4 nodes/thread ----------------
__global__ __launch_bounds__(256) void k_mgru(const float* __restrict__ agg,
                                              const float* __restrict__ cnt,
                                              const float* __restrict__ node,
                                              const float* __restrict__ rootW,
                                              const float* __restrict__ convb,
                                              const float* __restrict__ WihT,
                                              const float* __restrict__ WhhT,
                                              const float* __restrict__ bih,
                                              const float* __restrict__ bhh,
                                              float* __restrict__ hOut) {
    __shared__ float hs[16][68];
    __shared__ float ms[16][68];
    const int tid = threadIdx.x;
    const int d = tid & 63, sub = tid >> 6;
    const int nb = blockIdx.x * 16;
    const int r0 = sub * 4;

#pragma unroll
    for (int j = 0; j < 4; j++)
        hs[r0 + j][d] = node[(size_t)(nb + r0 + j) * 64 + d];
    __syncthreads();

    {
        float root[4] = {0.f, 0.f, 0.f, 0.f};
        for (int i = 0; i < 64; i++) {
            float wv = rootW[i * 64 + d];
#pragma unroll
            for (int j = 0; j < 4; j++) root[j] += hs[r0 + j][i] * wv;
        }
        float cb = convb[d];
#pragma unroll
        for (int j = 0; j < 4; j++) {
            int n = nb + r0 + j;
            float inv = 1.f / fmaxf(cnt[n], 1.f);
            ms[r0 + j][d] = fmaxf(agg[(size_t)n * 64 + d] * inv + cb + root[j], 0.f);
        }
    }
    __syncthreads();

    float ir[4], iz[4], in_[4], hr[4], hz[4], hn[4];
    {
        float bi0 = bih[d], bi1 = bih[64 + d], bi2 = bih[128 + d];
        float bh0 = bhh[d], bh1 = bhh[64 + d], bh2 = bhh[128 + d];
#pragma unroll
        for (int j = 0; j < 4; j++) {
            ir[j] = bi0; iz[j] = bi1; in_[j] = bi2;
            hr[j] = bh0; hz[j] = bh1; hn[j] = bh2;
        }
    }
    for (int i = 0; i < 64; i++) {
        float wi0 = WihT[i * 192 + d];
        float wi1 = WihT[i * 192 + 64 + d];
        float wi2 = WihT[i * 192 + 128 + d];
        float wh0 = WhhT[i * 192 + d];
        float wh1 = WhhT[i * 192 + 64 + d];
        float wh2 = WhhT[i * 192 + 128 + d];
#pragma unroll
        for (int j = 0; j < 4; j++) {
            float mi = ms[r0 + j][i], hi = hs[r0 + j][i];
            ir[j] += mi * wi0; iz[j] += mi * wi1; in_[j] += mi * wi2;
            hr[j] += hi * wh0; hz[j] += hi * wh1; hn[j] += hi * wh2;
        }
    }
#pragma unroll
    for (int j = 0; j < 4; j++) {
        float r = sigm(ir[j] + hr[j]);
        float z = sigm(iz[j] + hz[j]);
        float nn = tanhf(in_[j] + r * hn[j]);
        hOut[(size_t)(nb + r0 + j) * 64 + d] = (1.f - z) * nn + z * hs[r0 + j][d];
    }
}

// ---------------- Set2Set LSTM cell; WihT2 [128,256], WhhT2 [64,256] ----------------
__global__ void k_lstm(const float* qstar, const float* hlIn,
                       const float* WihT2, const float* WhhT2,
                       const float* bih, const float* bhh,
                       float* cl, float* hlOut) {
    int g = blockIdx.x * 256 + threadIdx.x;   // b*64+d
    int b = g >> 6, d = g & 63;
    const float* qv = qstar + (size_t)b * 128;
    const float* hr = hlIn + (size_t)b * 64;
    float gate[4];
    for (int gg = 0; gg < 4; gg++) {
        int row = gg * 64 + d;
        float acc = bih[row] + bhh[row];
        for (int j = 0; j < 128; j++) acc += qv[j] * WihT2[j * 256 + row];
        for (int j = 0; j < 64; j++) acc += hr[j] * WhhT2[j * 256 + row];
        gate[gg] = acc;
    }
    float i_ = sigm(gate[0]), f_ = sigm(gate[1]);
    float g_ = tanhf(gate[2]), o_ = sigm(gate[3]);
    float c = f_ * cl[g] + i_ * g_;
    cl[g] = c;
    hlOut[g] = o_ * tanhf(c);
}

// ---------------- e[n] = dot(node[n], q[batch[n]]) ----------------
__global__ void k_escore(const float* node, const float* q, const int* batch, float* e) {
    int tid = threadIdx.x;
    int n = blockIdx.x * 4 + (tid >> 6);
    int lane = tid & 63;
    int b = batch[n];
    float p = node[(size_t)n * 64 + lane] * q[(size_t)b * 64 + lane];
    for (int o = 32; o > 0; o >>= 1) p += __shfl_xor(p, o);
    if (lane == 0) e[n] = p;
}

// ---------------- segment softmax + weighted readout, one wave per graph ----------------
__global__ void k_pool(const float* node, const float* e, const int* batch,
                       const float* q, float* qstar) {
    int b = blockIdx.x; int lane = threadIdx.x;  // 64 threads
    int lo = 0, hi = NN_;
    while (lo < hi) { int mid = (lo + hi) >> 1; if (batch[mid] < b) lo = mid + 1; else hi = mid; }
    int start = lo;
    lo = start; hi = NN_;
    while (lo < hi) { int mid = (lo + hi) >> 1; if (batch[mid] < b + 1) lo = mid + 1; else hi = mid; }
    int end = lo;
    float r = 0.f;
    if (end > start) {
        float mx = -1e30f;
        for (int n = start + lane; n < end; n += 64) mx = fmaxf(mx, e[n]);
        for (int o = 32; o > 0; o >>= 1) mx = fmaxf(mx, __shfl_xor(mx, o));
        float den = 0.f;
        for (int n = start + lane; n < end; n += 64) den += expf(e[n] - mx);
        for (int o = 32; o > 0; o >>= 1) den += __shfl_xor(den, o);
        float inv = 1.f / den;
        for (int n = start; n < end; n++) {
            float wgt = expf(e[n] - mx) * inv;
            r += wgt * node[(size_t)n * 64 + lane];
        }
    }
    qstar[(size_t)b * 128 + lane] = q[(size_t)b * 64 + lane];
    qstar[(size_t)b * 128 + 64 + lane] = r;
}

// ---------------- head ----------------
__global__ void k_fc(const float* qstar, const float* W1, const float* b1,
                     const float* W2, const float* b2, float* out) {
    __shared__ float hid[128];
    int b = blockIdx.x; int t = threadIdx.x;  // 128 threads
    const float* qr = qstar + (size_t)b * 128;
    float acc = b1[t];
    const float* wr = W1 + (size_t)t * 128;
    for (int k = 0; k < 128; k++) acc += qr[k] * wr[k];
    hid[t] = fmaxf(acc, 0.f);
    __syncthreads();
    if (t < 64) {
        float s = hid[t] * W2[t] + hid[t + 64] * W2[t + 64];
        for (int o = 32; o > 0; o >>= 1) s += __shfl_xor(s, o);
        if (t == 0) out[b] = s + b2[0];
    }
}

extern "C" void kernel_launch(void* const* d_in, const int* in_sizes, int n_in,
                              void* d_out, int out_size, void* d_ws, size_t ws_size,
                              hipStream_t stream) {
    const float* x     = (const float*)d_in[0];
    const int*   ei    = (const int*)d_in[1];
    const float* ea    = (const float*)d_in[2];
    const int*   batch = (const int*)d_in[3];
    const float* lin0W = (const float*)d_in[4];
    const float* lin0b = (const float*)d_in[5];
    const float* e1W   = (const float*)d_in[6];
    const float* e1b   = (const float*)d_in[7];
    const float* e2W   = (const float*)d_in[8];
    const float* e2b   = (const float*)d_in[9];
    const float* rootW = (const float*)d_in[10];
    const float* convb = (const float*)d_in[11];
    const float* gWih  = (const float*)d_in[12];
    const float* gWhh  = (const float*)d_in[13];
    const float* gbih  = (const float*)d_in[14];
    const float* gbhh  = (const float*)d_in[15];
    const float* lWih  = (const float*)d_in[16];
    const float* lWhh  = (const float*)d_in[17];
    const float* lbih  = (const float*)d_in[18];
    const float* lbhh  = (const float*)d_in[19];
    const float* fc1W  = (const float*)d_in[20];
    const float* fc1b  = (const float*)d_in[21];
    const float* fc2W  = (const float*)d_in[22];
    const float* fc2b  = (const float*)d_in[23];
    const int* src = ei;
    const int* dst = ei + NE_;

    // workspace carve (~41 MB)
    char* p = (char*)d_ws;
    auto alloc = [&](size_t bytes) -> char* {
        char* r = p; p += (bytes + 255) & ~(size_t)255; return r;
    };
    unsigned short* Bhat3 = (unsigned short*)alloc((size_t)524288 * 2);        // 1.05 MB
    unsigned short* Hhat  = (unsigned short*)alloc((size_t)NE_ * 128 * 2);     // 12.6 MB
    float* nodeA  = (float*)alloc((size_t)NN_ * 64 * 4);
    float* nodeB  = (float*)alloc((size_t)NN_ * 64 * 4);
    float* aggb   = (float*)alloc((size_t)NN_ * 64 * 4);
    float* cnt    = (float*)alloc((size_t)NN_ * 4);
    float* ebuf   = (float*)alloc((size_t)NN_ * 4);
    float* WihT   = (float*)alloc(192 * 64 * 4);
    float* WhhT   = (float*)alloc(192 * 64 * 4);
    float* WihT2  = (float*)alloc(256 * 128 * 4);
    float* WhhT2  = (float*)alloc(256 * 64 * 4);
    float* qstar  = (float*)alloc((size_t)NG_ * 128 * 4);  // qstar,hlA,hlB,clb contiguous
    float* hlA    = (float*)alloc((size_t)NG_ * 64 * 4);
    float* hlB    = (float*)alloc((size_t)NG_ * 64 * 4);
    float* clb    = (float*)alloc((size_t)NG_ * 64 * 4);

    k_zero<<<(NN_ + 255) / 256, 256, 0, stream>>>(cnt, NN_);
    k_zero<<<(NG_ * 320 + 255) / 256, 256, 0, stream>>>(qstar, NG_ * 320);
    k_lin0<<<NN_ * 64 / 256, 256, 0, stream>>>(x, lin0W, lin0b, nodeA);
    k_cnt<<<NE_ / 256, 256, 0, stream>>>(dst, cnt);
    k_t192<<<48, 256, 0, stream>>>(gWih, WihT);
    k_t192<<<48, 256, 0, stream>>>(gWhh, WhhT);
    k_tlih<<<128, 256, 0, stream>>>(lWih, WihT2);
    k_tlhh<<<64, 256, 0, stream>>>(lWhh, WhhT2);
    k_bhat3<<<524288 / 256, 256, 0, stream>>>(e2W, Bhat3);
    // FIX (R15 bug): grid must cover gi < (NE_/16)*4 = 12288 -> NE_/16 = 3072 blocks (4 gi each)
    k_he<<<NE_ / 16, 256, 0, stream>>>(ea, e1W, e1b, Hhat);   // once — iteration-invariant

    float* curF = nodeA; float* nxtF = nodeB;
    for (int it = 0; it < 3; it++) {
        k_zero<<<NN_ * 64 / 256, 256, 0, stream>>>(aggb, NN_ * 64);
        k_convr<<<NE_ / 64, 256, 0, stream>>>(curF, Hhat, Bhat3, e2b, src, dst, aggb);
        k_mgru<<<NN_ / 16, 256, 0, stream>>>(aggb, cnt, curF, rootW, convb,
                                             WihT, WhhT, gbih, gbhh, nxtF);
        float* tf = curF; curF = nxtF; nxtF = tf;
    }

    float* hcur = hlA; float* hnxt = hlB;
    for (int s = 0; s < 3; s++) {
        k_lstm<<<NG_ * 64 / 256, 256, 0, stream>>>(qstar, hcur, WihT2, WhhT2, lbih, lbhh, clb, hnxt);
        k_escore<<<NN_ / 4, 256, 0, stream>>>(curF, hnxt, batch, ebuf);
        k_pool<<<NG_, 64, 0, stream>>>(curF, ebuf, batch, hnxt, qstar);
        float* t = hcur; hcur = hnxt; hnxt = t;
    }
    k_fc<<<NG_, 128, 0, stream>>>(qstar, fc1W, fc1b, fc2W, fc2b, (float*)d_out);
}

// Round 17
// 522.998 us; speedup vs baseline: 20.3335x; 1.1641x over previous
//
#include <hip/hip_runtime.h>
#include <math.h>

#define NN_ 32768      // nodes
#define NE_ 49152      // edges
#define NG_ 1024       // graphs

typedef short bh8 __attribute__((ext_vector_type(8)));   // 8 bf16 bit-patterns (4 VGPR)
typedef float f32x4 __attribute__((ext_vector_type(4)));

__device__ __forceinline__ unsigned short f2bfu(float f) {   // RNE float->bf16 bits
    union { float f; unsigned int i; } x; x.f = f;
    unsigned int u = x.i;
    u += 0x7FFFu + ((u >> 16) & 1u);
    return (unsigned short)(u >> 16);
}
__device__ __forceinline__ float sigm(float x) { return 1.f / (1.f + expf(-x)); }

// Kept for harness compatibility (unused).
__global__ void MPNN_78632261256134_kernel() {}

// ---------------- zero fill ----------------
__global__ void k_zero(float* p, int n) {
    int i = blockIdx.x * 256 + threadIdx.x;
    if (i < n) p[i] = 0.f;
}

// ---------------- lin0 ----------------
__global__ void k_lin0(const float* x, const float* W, const float* b, float* node) {
    int g = blockIdx.x * 256 + threadIdx.x;   // n*64+d
    int n = g >> 6, d = g & 63;
    const float* xr = x + n * 14;
    const float* wr = W + d * 14;
    float acc = b[d];
    for (int i = 0; i < 14; i++) acc += xr[i] * wr[i];
    node[g] = fmaxf(acc, 0.f);
}

// ---------------- in-degree count ----------------
__global__ void k_cnt(const int* dst, float* cnt) {
    int e = blockIdx.x * 256 + threadIdx.x;
    if (e < NE_) atomicAdd(&cnt[dst[e]], 1.0f);
}

// ---------------- fused weight transposes (4 kernels -> 1) ----------------
// [0,12288): gWih [192,64]->WihT [64,192]; [12288,24576): gWhh likewise;
// [24576,57344): lWih [256,128]->WihT2 [128,256]; [57344,73728): lWhh [256,64]->WhhT2 [64,256]
__global__ void k_tw(const float* gWih, const float* gWhh, float* WihT, float* WhhT,
                     const float* lWih, const float* lWhh, float* WihT2, float* WhhT2) {
    int t = blockIdx.x * 256 + threadIdx.x;
    if (t < 12288) {
        int gr = t >> 6, i = t & 63; WihT[i * 192 + gr] = gWih[t];
    } else if (t < 24576) {
        int u = t - 12288; int gr = u >> 6, i = u & 63; WhhT[i * 192 + gr] = gWhh[u];
    } else if (t < 57344) {
        int u = t - 24576; int r = u >> 7, c = u & 127; WihT2[c * 256 + r] = lWih[u];
    } else if (t < 73728) {
        int u = t - 57344; int r = u >> 6, c = u & 63; WhhT2[c * 256 + r] = lWhh[u];
    }
}

// ---------------- Bhat3: frag-contiguous bf16 B [s][w][t][lane][8] ----------------
__global__ void k_bhat3(const float* e2W, unsigned short* Bhat3) {
    int idx = blockIdx.x * 256 + threadIdx.x;   // < 524288
    if (idx >= 64 * 4 * 4 * 64 * 8) return;
    int j = idx & 7, lane = (idx >> 3) & 63, t = (idx >> 9) & 3, w = (idx >> 11) & 3, s = idx >> 13;
    int row = s * 64 + w * 16 + (lane & 15);
    int k = t * 32 + (lane >> 4) * 8 + j;
    Bhat3[idx] = f2bfu(e2W[row * 128 + k]);
}

// ---------------- Hhat: frag-ready He (iteration-invariant, computed once) ----------------
// gi = etile*4+t; grid must cover gi < (NE_/16)*4 = 12288 -> NE_/16 blocks of 4 gi.
__global__ __launch_bounds__(256) void k_he(const float* __restrict__ ea,
                                            const float* __restrict__ e1W,
                                            const float* __restrict__ e1b,
                                            unsigned short* __restrict__ Hhat) {
    int tid = threadIdx.x;
    int lane = tid & 63, sub = tid >> 6;
    int gi = blockIdx.x * 4 + sub;            // < 12288
    int etile = gi >> 2, t = gi & 3;
    int e = etile * 16 + (lane & 15), quad = lane >> 4;
    const float* ar = ea + (size_t)e * 4;
    float a0 = ar[0], a1 = ar[1], a2 = ar[2], a3 = ar[3];
    union { unsigned short u[8]; uint4 q; } o;
#pragma unroll
    for (int j = 0; j < 8; j++) {
        int c = t * 32 + quad * 8 + j;
        const float* wr = e1W + c * 4;
        float h = e1b[c] + a0 * wr[0] + a1 * wr[1] + a2 * wr[2] + a3 * wr[3];
        o.u[j] = f2bfu(fmaxf(h, 0.f));
    }
    *(uint4*)(Hhat + (size_t)gi * 512 + lane * 8) = o.q;
}

// ---------------- MFMA NNConv, register-direct B, NO barriers in K-loop ----------------
__global__ __launch_bounds__(256) void k_convr(const float* __restrict__ node,
                                               const unsigned short* __restrict__ Hhat,
                                               const unsigned short* __restrict__ Bhat3,
                                               const float* __restrict__ e2b,
                                               const int* __restrict__ src,
                                               const int* __restrict__ dst,
                                               float* __restrict__ agg) {
    __shared__ __align__(16) float xs[64 * 68];   // xs[s][e]
    __shared__ int dst_s[64];

    const int tid = threadIdx.x;
    const int eb = blockIdx.x * 64;
    const int lane = tid & 63, w = tid >> 6;
    const int quad = lane >> 4, mrow = lane & 15;

    {
        int r = tid >> 2, c = tid & 3;
        int s = src[eb + r];
        const float* nr = node + (size_t)s * 64 + c * 16;
#pragma unroll
        for (int j = 0; j < 16; j++) xs[(c * 16 + j) * 68 + r] = nr[j];
        if (tid < 64) dst_s[tid] = dst[eb + tid];
    }

    bh8 af[4][4];
#pragma unroll
    for (int mt = 0; mt < 4; mt++)
#pragma unroll
        for (int t = 0; t < 4; t++)
            af[mt][t] = *(const bh8*)(const void*)(
                Hhat + (size_t)(((eb >> 4) + mt) * 4 + t) * 512 + lane * 8);
    __syncthreads();   // the ONLY barrier

    const f32x4 z4 = {0.f, 0.f, 0.f, 0.f};
    f32x4 msg[4];
#pragma unroll
    for (int mt = 0; mt < 4; mt++) msg[mt] = z4;

    bh8 bn[4];
#pragma unroll
    for (int t = 0; t < 4; t++)
        bn[t] = *(const bh8*)(const void*)(Bhat3 + (size_t)((0 * 4 + w) * 4 + t) * 512 + lane * 8);
    float bbn = e2b[w * 16 + mrow];

    for (int s = 0; s < 64; s++) {
        bh8 bc[4];
#pragma unroll
        for (int t = 0; t < 4; t++) bc[t] = bn[t];
        const float bb = bbn;
        if (s < 63) {
#pragma unroll
            for (int t = 0; t < 4; t++)
                bn[t] = *(const bh8*)(const void*)(
                    Bhat3 + (size_t)(((s + 1) * 4 + w) * 4 + t) * 512 + lane * 8);
            bbn = e2b[(s + 1) * 64 + w * 16 + mrow];
        }

        f32x4 acc[4];
#pragma unroll
        for (int t = 0; t < 4; t++)
#pragma unroll
            for (int mt = 0; mt < 4; mt++)
                acc[mt] = __builtin_amdgcn_mfma_f32_16x16x32_bf16(
                    af[mt][t], bc[t], (t == 0) ? z4 : acc[mt], 0, 0, 0);

#pragma unroll
        for (int mt = 0; mt < 4; mt++) {
            f32x4 xv = *(const f32x4*)(const void*)(xs + s * 68 + mt * 16 + quad * 4);
#pragma unroll
            for (int r = 0; r < 4; r++)
                msg[mt][r] += xv[r] * (acc[mt][r] + bb);
        }
    }

#pragma unroll
    for (int mt = 0; mt < 4; mt++)
#pragma unroll
        for (int r = 0; r < 4; r++)
            atomicAdd(agg + (size_t)dst_s[mt * 16 + quad * 4 + r] * 64 + w * 16 + mrow,
                      msg[mt][r]);
}

// ---------------- fused m+GRU, transposed LDS (broadcast b128 reads) ----------------
// 16 nodes/block, thread (sub=tid>>6, d=tid&63) handles nodes sub*4..+3 at dim d.
// msT/hsT are [i][node] stride 20 -> wave-wide reads of msT[i][r0..r0+3] are broadcast b128.
__global__ __launch_bounds__(256) void k_mgru(const float* __restrict__ agg,
                                              const float* __restrict__ cnt,
                                              const float* __restrict__ node,
                                              const float* __restrict__ rootW,
                                              const float* __restrict__ convb,
                                              const float* __restrict__ WihT,
                                              const float* __restrict__ WhhT,
                                              const float* __restrict__ bih,
                                              const float* __restrict__ bhh,
                                              float* __restrict__ hOut) {
    __shared__ __align__(16) float hsT[64][20];   // hsT[i][node]
    __shared__ __align__(16) float msT[64][20];
    const int tid = threadIdx.x;
    const int d = tid & 63, sub = tid >> 6;
    const int nb = blockIdx.x * 16;
    const int r0 = sub * 4;

    {   // stage h transposed: coalesced global reads, one b128 LDS store
        f32x4 hv;
#pragma unroll
        for (int j = 0; j < 4; j++)
            hv[j] = node[(size_t)(nb + r0 + j) * 64 + d];
        *(f32x4*)&hsT[d][r0] = hv;
    }
    __syncthreads();

    {   // m = relu(agg/cnt + h@rootW + convb); rootW load shared, hsT broadcast
        f32x4 root = {0.f, 0.f, 0.f, 0.f};
        for (int i = 0; i < 64; i++) {
            float wv = rootW[i * 64 + d];
            f32x4 h4 = *(const f32x4*)&hsT[i][r0];
#pragma unroll
            for (int j = 0; j < 4; j++) root[j] += h4[j] * wv;
        }
        float cb = convb[d];
        f32x4 mval;
#pragma unroll
        for (int j = 0; j < 4; j++) {
            int n = nb + r0 + j;
            float inv = 1.f / fmaxf(cnt[n], 1.f);
            mval[j] = fmaxf(agg[(size_t)n * 64 + d] * inv + cb + root[j], 0.f);
        }
        *(f32x4*)&msT[d][r0] = mval;
    }
    __syncthreads();

    float ir[4], iz[4], in_[4], hr[4], hz[4], hn[4];
    {
        float bi0 = bih[d], bi1 = bih[64 + d], bi2 = bih[128 + d];
        float bh0 = bhh[d], bh1 = bhh[64 + d], bh2 = bhh[128 + d];
#pragma unroll
        for (int j = 0; j < 4; j++) {
            ir[j] = bi0; iz[j] = bi1; in_[j] = bi2;
            hr[j] = bh0; hz[j] = bh1; hn[j] = bh2;
        }
    }
    for (int i = 0; i < 64; i++) {
        float wi0 = WihT[i * 192 + d];
        float wi1 = WihT[i * 192 + 64 + d];
        float wi2 = WihT[i * 192 + 128 + d];
        float wh0 = WhhT[i * 192 + d];
        float wh1 = WhhT[i * 192 + 64 + d];
        float wh2 = WhhT[i * 192 + 128 + d];
        f32x4 m4 = *(const f32x4*)&msT[i][r0];   // broadcast
        f32x4 h4 = *(const f32x4*)&hsT[i][r0];   // broadcast
#pragma unroll
        for (int j = 0; j < 4; j++) {
            ir[j] += m4[j] * wi0; iz[j] += m4[j] * wi1; in_[j] += m4[j] * wi2;
            hr[j] += h4[j] * wh0; hz[j] += h4[j] * wh1; hn[j] += h4[j] * wh2;
        }
    }
    f32x4 hold = *(const f32x4*)&hsT[d][r0];
#pragma unroll
    for (int j = 0; j < 4; j++) {
        float r = sigm(ir[j] + hr[j]);
        float z = sigm(iz[j] + hz[j]);
        float nn = tanhf(in_[j] + r * hn[j]);
        hOut[(size_t)(nb + r0 + j) * 64 + d] = (1.f - z) * nn + z * hold[j];
    }
}

// ---------------- fused Set2Set step: LSTM + escore + online-softmax readout ----------------
// one block (64 threads = 1 wave) per graph b; hl/cl/qstar updated in place (per-block rows).
__global__ __launch_bounds__(64) void k_s2s(const float* __restrict__ node,
                                            const int* __restrict__ batch,
                                            const float* __restrict__ WihT2,
                                            const float* __restrict__ WhhT2,
                                            const float* __restrict__ bih,
                                            const float* __restrict__ bhh,
                                            float* __restrict__ cl,
                                            float* __restrict__ hl,
                                            float* __restrict__ qstar) {
    __shared__ float qvs[128];
    __shared__ float hls[64];
    const int b = blockIdx.x, lane = threadIdx.x;

    qvs[lane] = qstar[(size_t)b * 128 + lane];
    qvs[64 + lane] = qstar[(size_t)b * 128 + 64 + lane];
    hls[lane] = hl[(size_t)b * 64 + lane];
    __syncthreads();

    // LSTM gates: acc[gg] over q (128) and hl (64); weight rows coalesced
    float acc0 = bih[lane] + bhh[lane];
    float acc1 = bih[64 + lane] + bhh[64 + lane];
    float acc2 = bih[128 + lane] + bhh[128 + lane];
    float acc3 = bih[192 + lane] + bhh[192 + lane];
    for (int j = 0; j < 128; j++) {
        float qj = qvs[j];
        const float* wr = WihT2 + (size_t)j * 256;
        acc0 += qj * wr[lane];
        acc1 += qj * wr[64 + lane];
        acc2 += qj * wr[128 + lane];
        acc3 += qj * wr[192 + lane];
    }
    for (int j = 0; j < 64; j++) {
        float hj = hls[j];
        const float* wr = WhhT2 + (size_t)j * 256;
        acc0 += hj * wr[lane];
        acc1 += hj * wr[64 + lane];
        acc2 += hj * wr[128 + lane];
        acc3 += hj * wr[192 + lane];
    }
    float c = sigm(acc1) * cl[(size_t)b * 64 + lane] + sigm(acc0) * tanhf(acc2);
    cl[(size_t)b * 64 + lane] = c;
    float q = sigm(acc3) * tanhf(c);
    hl[(size_t)b * 64 + lane] = q;

    // segment bounds (binary search over sorted batch)
    int lo = 0, hi = NN_;
    while (lo < hi) { int mid = (lo + hi) >> 1; if (batch[mid] < b) lo = mid + 1; else hi = mid; }
    int start = lo;
    lo = start; hi = NN_;
    while (lo < hi) { int mid = (lo + hi) >> 1; if (batch[mid] < b + 1) lo = mid + 1; else hi = mid; }
    int end = lo;

    // online softmax readout: one coalesced node-row read serves dot AND accumulate
    float r_acc = 0.f, m_run = -1e30f, l_run = 0.f;
    for (int n = start; n < end; n++) {
        float nv = node[(size_t)n * 64 + lane];
        float p = nv * q;
#pragma unroll
        for (int o = 32; o > 0; o >>= 1) p += __shfl_xor(p, o);
        float m_new = fmaxf(m_run, p);
        float sc = expf(m_run - m_new);
        float wgt = expf(p - m_new);
        l_run = l_run * sc + wgt;
        r_acc = r_acc * sc + wgt * nv;
        m_run = m_new;
    }
    qstar[(size_t)b * 128 + lane] = q;
    qstar[(size_t)b * 128 + 64 + lane] = (end > start) ? r_acc / l_run : 0.f;
}

// ---------------- head ----------------
__global__ void k_fc(const float* qstar, const float* W1, const float* b1,
                     const float* W2, const float* b2, float* out) {
    __shared__ float hid[128];
    int b = blockIdx.x; int t = threadIdx.x;  // 128 threads
    const float* qr = qstar + (size_t)b * 128;
    float acc = b1[t];
    const float* wr = W1 + (size_t)t * 128;
    for (int k = 0; k < 128; k++) acc += qr[k] * wr[k];
    hid[t] = fmaxf(acc, 0.f);
    __syncthreads();
    if (t < 64) {
        float s = hid[t] * W2[t] + hid[t + 64] * W2[t + 64];
        for (int o = 32; o > 0; o >>= 1) s += __shfl_xor(s, o);
        if (t == 0) out[b] = s + b2[0];
    }
}

extern "C" void kernel_launch(void* const* d_in, const int* in_sizes, int n_in,
                              void* d_out, int out_size, void* d_ws, size_t ws_size,
                              hipStream_t stream) {
    const float* x     = (const float*)d_in[0];
    const int*   ei    = (const int*)d_in[1];
    const float* ea    = (const float*)d_in[2];
    const int*   batch = (const int*)d_in[3];
    const float* lin0W = (const float*)d_in[4];
    const float* lin0b = (const float*)d_in[5];
    const float* e1W   = (const float*)d_in[6];
    const float* e1b   = (const float*)d_in[7];
    const float* e2W   = (const float*)d_in[8];
    const float* e2b   = (const float*)d_in[9];
    const float* rootW = (const float*)d_in[10];
    const float* convb = (const float*)d_in[11];
    const float* gWih  = (const float*)d_in[12];
    const float* gWhh  = (const float*)d_in[13];
    const float* gbih  = (const float*)d_in[14];
    const float* gbhh  = (const float*)d_in[15];
    const float* lWih  = (const float*)d_in[16];
    const float* lWhh  = (const float*)d_in[17];
    const float* lbih  = (const float*)d_in[18];
    const float* lbhh  = (const float*)d_in[19];
    const float* fc1W  = (const float*)d_in[20];
    const float* fc1b  = (const float*)d_in[21];
    const float* fc2W  = (const float*)d_in[22];
    const float* fc2b  = (const float*)d_in[23];
    const int* src = ei;
    const int* dst = ei + NE_;

    // workspace carve (~41 MB)
    char* p = (char*)d_ws;
    auto alloc = [&](size_t bytes) -> char* {
        char* r = p; p += (bytes + 255) & ~(size_t)255; return r;
    };
    unsigned short* Bhat3 = (unsigned short*)alloc((size_t)524288 * 2);        // 1.05 MB
    unsigned short* Hhat  = (unsigned short*)alloc((size_t)NE_ * 128 * 2);     // 12.6 MB
    float* nodeA  = (float*)alloc((size_t)NN_ * 64 * 4);
    float* nodeB  = (float*)alloc((size_t)NN_ * 64 * 4);
    float* aggb   = (float*)alloc((size_t)NN_ * 64 * 4);
    float* cnt    = (float*)alloc((size_t)NN_ * 4);
    float* WihT   = (float*)alloc(192 * 64 * 4);
    float* WhhT   = (float*)alloc(192 * 64 * 4);
    float* WihT2  = (float*)alloc(256 * 128 * 4);
    float* WhhT2  = (float*)alloc(256 * 64 * 4);
    float* qstar  = (float*)alloc((size_t)NG_ * 128 * 4);  // qstar | hl | cl contiguous
    float* hl     = (float*)alloc((size_t)NG_ * 64 * 4);
    float* clb    = (float*)alloc((size_t)NG_ * 64 * 4);

    k_zero<<<(NN_ + 255) / 256, 256, 0, stream>>>(cnt, NN_);
    k_zero<<<(NG_ * 256 + 255) / 256, 256, 0, stream>>>(qstar, NG_ * 256);  // qstar+hl+cl
    k_lin0<<<NN_ * 64 / 256, 256, 0, stream>>>(x, lin0W, lin0b, nodeA);
    k_cnt<<<NE_ / 256, 256, 0, stream>>>(dst, cnt);
    k_tw<<<288, 256, 0, stream>>>(gWih, gWhh, WihT, WhhT, lWih, lWhh, WihT2, WhhT2);
    k_bhat3<<<524288 / 256, 256, 0, stream>>>(e2W, Bhat3);
    k_he<<<NE_ / 16, 256, 0, stream>>>(ea, e1W, e1b, Hhat);   // once — iteration-invariant

    float* curF = nodeA; float* nxtF = nodeB;
    for (int it = 0; it < 3; it++) {
        k_zero<<<NN_ * 64 / 256, 256, 0, stream>>>(aggb, NN_ * 64);
        k_convr<<<NE_ / 64, 256, 0, stream>>>(curF, Hhat, Bhat3, e2b, src, dst, aggb);
        k_mgru<<<NN_ / 16, 256, 0, stream>>>(aggb, cnt, curF, rootW, convb,
                                             WihT, WhhT, gbih, gbhh, nxtF);
        float* tf = curF; curF = nxtF; nxtF = tf;
    }

    for (int s = 0; s < 3; s++)
        k_s2s<<<NG_, 64, 0, stream>>>(curF, batch, WihT2, WhhT2, lbih, lbhh, clb, hl, qstar);
    k_fc<<<NG_, 128, 0, stream>>>(qstar, fc1W, fc1b, fc2W, fc2b, (float*)d_out);
}